// Round 7
// baseline (105.390 us; speedup 1.0000x reference)
//
#include <hip/hip_runtime.h>

// AttentionHead: B=4, T=4096, C=1024, H=64, causal softmax(QK^T/8)V
// R7: attn5 = barrier-free flash attn, K/V read DIRECT from L2 (no LDS
// staging, no per-iter barriers), kv-split-4 across waves, 4-way exact
// merge in LDS. proj3 = 512x256, 32-row tiles, X register prefetch.

using bf16x8 = __attribute__((ext_vector_type(8))) short;
using bf16x4 = __attribute__((ext_vector_type(4))) short;
using f32x4  = __attribute__((ext_vector_type(4))) float;

#define QSCALE 0.1803368867f  // 0.125 * log2(e): softmax in exp2 domain

__device__ __forceinline__ unsigned short f2bf(float f) {
  union { float f; unsigned int u; } v; v.f = f;
  unsigned int r = v.u + 0x7fffu + ((v.u >> 16) & 1u);  // RNE
  return (unsigned short)(r >> 16);
}

__device__ __forceinline__ float fexp2(float x) {
#if __has_builtin(__builtin_amdgcn_exp2f)
  return __builtin_amdgcn_exp2f(x);
#else
  float r; asm("v_exp_f32 %0, %1" : "=v"(r) : "v"(x)); return r;
#endif
}

__device__ __forceinline__ f32x4 mfma16(bf16x4 a, bf16x4 b, f32x4 c) {
#if __has_builtin(__builtin_amdgcn_mfma_f32_16x16x16bf16_1k)
  return __builtin_amdgcn_mfma_f32_16x16x16bf16_1k(a, b, c, 0, 0, 0);
#else
  f32x4 d;
  asm volatile("v_mfma_f32_16x16x16_bf16 %0, %1, %2, %3"
               : "=v"(d) : "v"(a), "v"(b), "v"(c));
  return d;
#endif
}

// ---- proj3: 512 blocks x 256 thr; 32 rows x 192 cols; X reg-prefetch --
__global__ __launch_bounds__(256) void proj3_kernel(
    const float* __restrict__ X,  const float* __restrict__ Wk,
    const float* __restrict__ Wq, const float* __restrict__ Wv,
    const float* __restrict__ bk, const float* __restrict__ bq,
    const float* __restrict__ bv, unsigned short* __restrict__ Kr,
    unsigned short* __restrict__ Qs, unsigned short* __restrict__ Vt) {
  __shared__ __align__(16) unsigned short Xl[32 * 72];
  __shared__ __align__(16) unsigned short Wl[192 * 72];
  const int tid = threadIdx.x;
  const int m0  = blockIdx.x * 32;
  const int w   = tid >> 6;
  const int mt  = w & 1;          // 16-row half
  const int nh  = w >> 1;         // 96-col half
  const int ln  = tid & 63;
  const int l15 = ln & 15;
  const int l4  = ln >> 4;
  const int wn   = tid & 63;      // W staging: lane = n (coalesced)
  const int wk16 = (tid >> 6) * 16;
  const int xr0 = tid >> 4,          xc0 = tid & 15;
  const int xr1 = (tid + 256) >> 4,  xc1 = tid & 15;
  const f32x4 zero4 = {0.f, 0.f, 0.f, 0.f};

  f32x4 acc[6];
  #pragma unroll
  for (int i = 0; i < 6; ++i) acc[i] = zero4;

  float4 xp0 = *reinterpret_cast<const float4*>(X + (size_t)(m0 + xr0) * 1024 + xc0 * 4);
  float4 xp1 = *reinterpret_cast<const float4*>(X + (size_t)(m0 + xr1) * 1024 + xc1 * 4);

  for (int kb = 0; kb < 16; ++kb) {
    // write prefetched X tile (fp32 -> bf16)
    bf16x4 o0, o1;
    o0[0] = (short)f2bf(xp0.x); o0[1] = (short)f2bf(xp0.y);
    o0[2] = (short)f2bf(xp0.z); o0[3] = (short)f2bf(xp0.w);
    o1[0] = (short)f2bf(xp1.x); o1[1] = (short)f2bf(xp1.y);
    o1[2] = (short)f2bf(xp1.z); o1[3] = (short)f2bf(xp1.w);
    *reinterpret_cast<bf16x4*>(&Xl[xr0 * 72 + xc0 * 4]) = o0;
    *reinterpret_cast<bf16x4*>(&Xl[xr1 * 72 + xc1 * 4]) = o1;
    // stage W transposed (L2-resident)
    #pragma unroll
    for (int c = 0; c < 3; ++c) {
      const float* Wsrc = (c == 0) ? Wk : ((c == 1) ? Wq : Wv);
      bf16x8 w0, w1;
      #pragma unroll
      for (int j = 0; j < 8; ++j)
        w0[j] = (short)f2bf(Wsrc[(size_t)(kb * 64 + wk16 + j) * 64 + wn]);
      #pragma unroll
      for (int j = 0; j < 8; ++j)
        w1[j] = (short)f2bf(Wsrc[(size_t)(kb * 64 + wk16 + 8 + j) * 64 + wn]);
      *reinterpret_cast<bf16x8*>(&Wl[(c * 64 + wn) * 72 + wk16])     = w0;
      *reinterpret_cast<bf16x8*>(&Wl[(c * 64 + wn) * 72 + wk16 + 8]) = w1;
    }
    __syncthreads();
    if (kb < 15) {  // prefetch next X tile (flies over MFMA phase)
      xp0 = *reinterpret_cast<const float4*>(
          X + (size_t)(m0 + xr0) * 1024 + (kb + 1) * 64 + xc0 * 4);
      xp1 = *reinterpret_cast<const float4*>(
          X + (size_t)(m0 + xr1) * 1024 + (kb + 1) * 64 + xc1 * 4);
    }
    bf16x8 a0 = *reinterpret_cast<const bf16x8*>(&Xl[(mt * 16 + l15) * 72 + l4 * 8]);
    bf16x8 a1 = *reinterpret_cast<const bf16x8*>(&Xl[(mt * 16 + l15) * 72 + 32 + l4 * 8]);
    #pragma unroll
    for (int i = 0; i < 6; ++i) {
      int row = nh * 96 + i * 16 + l15;
      bf16x8 b0 = *reinterpret_cast<const bf16x8*>(&Wl[row * 72 + l4 * 8]);
      bf16x8 b1 = *reinterpret_cast<const bf16x8*>(&Wl[row * 72 + 32 + l4 * 8]);
      acc[i] = __builtin_amdgcn_mfma_f32_16x16x32_bf16(a0, b0, acc[i], 0, 0, 0);
      acc[i] = __builtin_amdgcn_mfma_f32_16x16x32_bf16(a1, b1, acc[i], 0, 0, 0);
    }
    __syncthreads();
  }
  #pragma unroll
  for (int i = 0; i < 6; ++i) {
    int j = nh * 96 + i * 16 + l15;
    int mr0 = m0 + mt * 16 + l4 * 4;
    if (j < 64) {
      #pragma unroll
      for (int r = 0; r < 4; ++r)
        Kr[(size_t)(mr0 + r) * 64 + j] = f2bf(acc[i][r] + bk[j]);
    } else if (j < 128) {
      int jq = j - 64;
      #pragma unroll
      for (int r = 0; r < 4; ++r)
        Qs[(size_t)(mr0 + r) * 64 + jq] = f2bf((acc[i][r] + bq[jq]) * QSCALE);
    } else {
      int h = j - 128;
      int bb = mr0 >> 12, t0 = mr0 & 4095;
      ushort4 o;
      o.x = f2bf(acc[i][0] + bv[h]); o.y = f2bf(acc[i][1] + bv[h]);
      o.z = f2bf(acc[i][2] + bv[h]); o.w = f2bf(acc[i][3] + bv[h]);
      *reinterpret_cast<ushort4*>(&Vt[((size_t)(bb * 64 + h)) * 4096 + t0]) = o;
    }
  }
}

// ---- attn5: barrier-free direct-L2 flash attn, kv-split-4 -------------
__global__ __launch_bounds__(256) void attn5_kernel(
    const unsigned short* __restrict__ Qs,
    const unsigned short* __restrict__ Kr,
    const unsigned short* __restrict__ Vt,
    float* __restrict__ out) {
  __shared__ float MO[3][2][16][68];   // partner O^T, [q][h] padded
  __shared__ float ML[3][2][2][16];    // partner {m,l}
  const int tid = threadIdx.x;
  const int w   = tid >> 6;            // kv residue class
  const int ln  = tid & 63;
  const int l15 = ln & 15;
  const int l4  = ln >> 4;
  const int bid = blockIdx.x;
  const int qt  = 127 - (bid >> 2);    // longest-first
  const int b   = bid & 3;             // batch pinned per XCD
  const int qbase  = qt * 32;
  const int ntiles = (qt >> 1) + 1;
  const f32x4 zero4 = {0.f, 0.f, 0.f, 0.f};

  // Q fragments for both 16-row halves (B-operand: n=q=l15, k=h)
  const unsigned short* Q0 = Qs + ((size_t)b * 4096 + qbase + l15) * 64;
  const bf16x8 qa0 = *reinterpret_cast<const bf16x8*>(Q0 + l4 * 8);
  const bf16x8 qa1 = *reinterpret_cast<const bf16x8*>(Q0 + 32 + l4 * 8);
  const bf16x8 qb0 = *reinterpret_cast<const bf16x8*>(Q0 + 1024 + l4 * 8);
  const bf16x8 qb1 = *reinterpret_cast<const bf16x8*>(Q0 + 1024 + 32 + l4 * 8);

  // per-lane base pointers (K: A-frag rows; V^T: A-frag rows per ht)
  const unsigned short* Kb  = Kr + ((size_t)b * 4096 + l15) * 64 + l4 * 8;
  const unsigned short* Vh0 = Vt + ((size_t)(b * 64) + l15) * 4096 + l4 * 4;
  const unsigned short* Vh1 = Vh0 + 16 * 4096;
  const unsigned short* Vh2 = Vh0 + 32 * 4096;
  const unsigned short* Vh3 = Vh0 + 48 * 4096;

  f32x4 accA[4], accB[4];
  #pragma unroll
  for (int i = 0; i < 4; ++i) { accA[i] = zero4; accB[i] = zero4; }
  float mA = -1e30f, lA = 0.f, mB = -1e30f, lB = 0.f;

  for (int t = w; t < ntiles; t += 4) {
    const unsigned short* Kt = Kb + (size_t)t * 4096;
    bf16x8 k0[4], k1[4];
    #pragma unroll
    for (int nt = 0; nt < 4; ++nt) {
      k0[nt] = *reinterpret_cast<const bf16x8*>(Kt + nt * 1024);
      k1[nt] = *reinterpret_cast<const bf16x8*>(Kt + nt * 1024 + 32);
    }
    // S^T = K Q^T for both halves: s[nt][r] = S[kv=nt*16+4*l4+r][q=l15]
    f32x4 sA[4], sB[4];
    #pragma unroll
    for (int i = 0; i < 4; ++i) { sA[i] = zero4; sB[i] = zero4; }
    __builtin_amdgcn_s_setprio(1);
    #pragma unroll
    for (int nt = 0; nt < 4; ++nt) {
      sA[nt] = __builtin_amdgcn_mfma_f32_16x16x32_bf16(k0[nt], qa0, sA[nt], 0, 0, 0);
      sA[nt] = __builtin_amdgcn_mfma_f32_16x16x32_bf16(k1[nt], qa1, sA[nt], 0, 0, 0);
      sB[nt] = __builtin_amdgcn_mfma_f32_16x16x32_bf16(k0[nt], qb0, sB[nt], 0, 0, 0);
      sB[nt] = __builtin_amdgcn_mfma_f32_16x16x32_bf16(k1[nt], qb1, sB[nt], 0, 0, 0);
    }
    __builtin_amdgcn_s_setprio(0);

    // V^T fragments (issued now, consumed after softmax -> latency hidden)
    const int toff = t * 64;
    bf16x4 vf0[4], vf1[4], vf2[4], vf3[4];
    #pragma unroll
    for (int nt = 0; nt < 4; ++nt) {
      vf0[nt] = *reinterpret_cast<const bf16x4*>(Vh0 + toff + nt * 16);
      vf1[nt] = *reinterpret_cast<const bf16x4*>(Vh1 + toff + nt * 16);
      vf2[nt] = *reinterpret_cast<const bf16x4*>(Vh2 + toff + nt * 16);
      vf3[nt] = *reinterpret_cast<const bf16x4*>(Vh3 + toff + nt * 16);
    }

    if (t == ntiles - 1) {  // causal mask (only last tile crosses diagonal)
      const int qmA = qbase + l15 - toff;
      #pragma unroll
      for (int nt = 0; nt < 4; ++nt)
        #pragma unroll
        for (int r = 0; r < 4; ++r) {
          int kvl = nt * 16 + 4 * l4 + r;
          if (kvl > qmA)      sA[nt][r] = -1e30f;
          if (kvl > qmA + 16) sB[nt][r] = -1e30f;
        }
    }

    // ---- online softmax, half A (lane-local 16 + 2 shfls)
    bf16x4 paA[4], paB[4];
    {
      float x0 = fmaxf(fmaxf(sA[0][0], sA[0][1]), fmaxf(sA[0][2], sA[0][3]));
      float x1 = fmaxf(fmaxf(sA[1][0], sA[1][1]), fmaxf(sA[1][2], sA[1][3]));
      float x2 = fmaxf(fmaxf(sA[2][0], sA[2][1]), fmaxf(sA[2][2], sA[2][3]));
      float x3 = fmaxf(fmaxf(sA[3][0], sA[3][1]), fmaxf(sA[3][2], sA[3][3]));
      float xm = fmaxf(fmaxf(x0, x1), fmaxf(x2, x3));
      xm = fmaxf(xm, __shfl_xor(xm, 16));
      xm = fmaxf(xm, __shfl_xor(xm, 32));
      float mn = fmaxf(mA, xm);
      float cc = fexp2(mA - mn);
      mA = mn; lA *= cc;
      #pragma unroll
      for (int ht = 0; ht < 4; ++ht)
        #pragma unroll
        for (int r = 0; r < 4; ++r) accA[ht][r] *= cc;
      float sum = 0.f;
      #pragma unroll
      for (int nt = 0; nt < 4; ++nt) {
        #pragma unroll
        for (int r = 0; r < 4; ++r) {
          float p = fexp2(sA[nt][r] - mA);
          sA[nt][r] = p;
          paA[nt][r] = (short)f2bf(p);
        }
        sum += (sA[nt][0] + sA[nt][1]) + (sA[nt][2] + sA[nt][3]);
      }
      sum += __shfl_xor(sum, 16);
      sum += __shfl_xor(sum, 32);
      lA += sum;
    }
    // ---- online softmax, half B
    {
      float x0 = fmaxf(fmaxf(sB[0][0], sB[0][1]), fmaxf(sB[0][2], sB[0][3]));
      float x1 = fmaxf(fmaxf(sB[1][0], sB[1][1]), fmaxf(sB[1][2], sB[1][3]));
      float x2 = fmaxf(fmaxf(sB[2][0], sB[2][1]), fmaxf(sB[2][2], sB[2][3]));
      float x3 = fmaxf(fmaxf(sB[3][0], sB[3][1]), fmaxf(sB[3][2], sB[3][3]));
      float xm = fmaxf(fmaxf(x0, x1), fmaxf(x2, x3));
      xm = fmaxf(xm, __shfl_xor(xm, 16));
      xm = fmaxf(xm, __shfl_xor(xm, 32));
      float mn = fmaxf(mB, xm);
      float cc = fexp2(mB - mn);
      mB = mn; lB *= cc;
      #pragma unroll
      for (int ht = 0; ht < 4; ++ht)
        #pragma unroll
        for (int r = 0; r < 4; ++r) accB[ht][r] *= cc;
      float sum = 0.f;
      #pragma unroll
      for (int nt = 0; nt < 4; ++nt) {
        #pragma unroll
        for (int r = 0; r < 4; ++r) {
          float p = fexp2(sB[nt][r] - mB);
          sB[nt][r] = p;
          paB[nt][r] = (short)f2bf(p);
        }
        sum += (sB[nt][0] + sB[nt][1]) + (sB[nt][2] + sB[nt][3]);
      }
      sum += __shfl_xor(sum, 16);
      sum += __shfl_xor(sum, 32);
      lB += sum;
    }

    // ---- O^T += V^T P^T (A = V-frag from L2, B = P in registers)
    __builtin_amdgcn_s_setprio(1);
    #pragma unroll
    for (int nt = 0; nt < 4; ++nt) {
      accA[0] = mfma16(vf0[nt], paA[nt], accA[0]);
      accA[1] = mfma16(vf1[nt], paA[nt], accA[1]);
      accA[2] = mfma16(vf2[nt], paA[nt], accA[2]);
      accA[3] = mfma16(vf3[nt], paA[nt], accA[3]);
      accB[0] = mfma16(vf0[nt], paB[nt], accB[0]);
      accB[1] = mfma16(vf1[nt], paB[nt], accB[1]);
      accB[2] = mfma16(vf2[nt], paB[nt], accB[2]);
      accB[3] = mfma16(vf3[nt], paB[nt], accB[3]);
    }
    __builtin_amdgcn_s_setprio(0);
  }

  // ---- 4-way exact merge (single barrier)
  if (w > 0) {
    #pragma unroll
    for (int ht = 0; ht < 4; ++ht) {
      *reinterpret_cast<f32x4*>(&MO[w - 1][0][l15][ht * 16 + 4 * l4]) = accA[ht];
      *reinterpret_cast<f32x4*>(&MO[w - 1][1][l15][ht * 16 + 4 * l4]) = accB[ht];
    }
    if (l4 == 0) {
      ML[w - 1][0][0][l15] = mA; ML[w - 1][0][1][l15] = lA;
      ML[w - 1][1][0][l15] = mB; ML[w - 1][1][1][l15] = lB;
    }
  }
  __syncthreads();
  if (w == 0) {
    #pragma unroll
    for (int hf = 0; hf < 2; ++hf) {
      float m = hf ? mB : mA;
      float l = hf ? lB : lA;
      float m0_ = ML[0][hf][0][l15], m1_ = ML[1][hf][0][l15], m2_ = ML[2][hf][0][l15];
      float mM = fmaxf(fmaxf(m, m0_), fmaxf(m1_, m2_));
      float aS = fexp2(m - mM);
      float a0 = fexp2(m0_ - mM), a1 = fexp2(m1_ - mM), a2 = fexp2(m2_ - mM);
      float lT = l * aS + ML[0][hf][1][l15] * a0 + ML[1][hf][1][l15] * a1
               + ML[2][hf][1][l15] * a2;
      float linv = 1.0f / lT;
      float* ob = out + ((size_t)b * 4096 + qbase + hf * 16 + l15) * 64;
      #pragma unroll
      for (int ht = 0; ht < 4; ++ht) {
        f32x4 ac = hf ? accB[ht] : accA[ht];
        f32x4 o0 = *reinterpret_cast<const f32x4*>(&MO[0][hf][l15][ht * 16 + 4 * l4]);
        f32x4 o1 = *reinterpret_cast<const f32x4*>(&MO[1][hf][l15][ht * 16 + 4 * l4]);
        f32x4 o2 = *reinterpret_cast<const f32x4*>(&MO[2][hf][l15][ht * 16 + 4 * l4]);
        float4 o;
        o.x = (ac[0] * aS + o0[0] * a0 + o1[0] * a1 + o2[0] * a2) * linv;
        o.y = (ac[1] * aS + o0[1] * a0 + o1[1] * a1 + o2[1] * a2) * linv;
        o.z = (ac[2] * aS + o0[2] * a0 + o1[2] * a1 + o2[2] * a2) * linv;
        o.w = (ac[3] * aS + o0[3] * a0 + o1[3] * a1 + o2[3] * a2) * linv;
        *reinterpret_cast<float4*>(ob + ht * 16 + 4 * l4) = o;
      }
    }
  }
}

// ---- Plan-B fallback: old proj (no Q) + attn with Q recompute ---------
template <bool WRITE_Q>
__global__ __launch_bounds__(256) void proj_kernel(
    const float* __restrict__ X,  const float* __restrict__ Wk,
    const float* __restrict__ Wq, const float* __restrict__ Wv,
    const float* __restrict__ bk, const float* __restrict__ bq,
    const float* __restrict__ bv, unsigned short* __restrict__ Kr,
    unsigned short* __restrict__ Qs, unsigned short* __restrict__ Vt) {
  constexpr int NT = WRITE_Q ? 12 : 8;
  constexpr int NC = NT / 4;
  __shared__ __align__(16) unsigned short Xl[64 * 72];
  __shared__ __align__(16) unsigned short Wl[NT * 16 * 72];
  const int tid = threadIdx.x;
  const int m0  = blockIdx.x * 64;
  const int w   = tid >> 6;
  const int ln  = tid & 63;
  const int l15 = ln & 15;
  const int l4  = ln >> 4;
  const f32x4 zero4 = {0.f, 0.f, 0.f, 0.f};
  f32x4 acc[NT];
  #pragma unroll
  for (int i = 0; i < NT; ++i) acc[i] = zero4;
  const int wn = tid & 63;
  const int wk = (tid >> 6) * 16;
  for (int kb = 0; kb < 16; ++kb) {
    __syncthreads();
    #pragma unroll
    for (int p = 0; p < 4; ++p) {
      int chunk = tid + p * 256;
      int r = chunk >> 4, c4 = chunk & 15;
      const float4 xv = *reinterpret_cast<const float4*>(
          X + (size_t)(m0 + r) * 1024 + kb * 64 + c4 * 4);
      bf16x4 o;
      o[0] = (short)f2bf(xv.x); o[1] = (short)f2bf(xv.y);
      o[2] = (short)f2bf(xv.z); o[3] = (short)f2bf(xv.w);
      *reinterpret_cast<bf16x4*>(&Xl[r * 72 + c4 * 4]) = o;
    }
    #pragma unroll
    for (int c = 0; c < NC; ++c) {
      const float* Wsrc = (c == 0) ? Wk : ((WRITE_Q && c == 1) ? Wq : Wv);
      bf16x8 w0, w1;
      #pragma unroll
      for (int j = 0; j < 8; ++j)
        w0[j] = (short)f2bf(Wsrc[(size_t)(kb * 64 + wk + j) * 64 + wn]);
      #pragma unroll
      for (int j = 0; j < 8; ++j)
        w1[j] = (short)f2bf(Wsrc[(size_t)(kb * 64 + wk + 8 + j) * 64 + wn]);
      *reinterpret_cast<bf16x8*>(&Wl[(c * 64 + wn) * 72 + wk])     = w0;
      *reinterpret_cast<bf16x8*>(&Wl[(c * 64 + wn) * 72 + wk + 8]) = w1;
    }
    __syncthreads();
    bf16x8 a0 = *reinterpret_cast<const bf16x8*>(&Xl[(w * 16 + l15) * 72 + l4 * 8]);
    bf16x8 a1 = *reinterpret_cast<const bf16x8*>(&Xl[(w * 16 + l15) * 72 + 32 + l4 * 8]);
    #pragma unroll
    for (int nt = 0; nt < NT; ++nt) {
      bf16x8 b0 = *reinterpret_cast<const bf16x8*>(&Wl[(nt * 16 + l15) * 72 + l4 * 8]);
      bf16x8 b1 = *reinterpret_cast<const bf16x8*>(&Wl[(nt * 16 + l15) * 72 + 32 + l4 * 8]);
      acc[nt] = __builtin_amdgcn_mfma_f32_16x16x32_bf16(a0, b0, acc[nt], 0, 0, 0);
      acc[nt] = __builtin_amdgcn_mfma_f32_16x16x32_bf16(a1, b1, acc[nt], 0, 0, 0);
    }
  }
  #pragma unroll
  for (int nt = 0; nt < NT; ++nt) {
    int j = nt * 16 + l15;
    #pragma unroll
    for (int r = 0; r < 4; ++r) {
      int m = m0 + w * 16 + l4 * 4 + r;
      float v = acc[nt][r];
      if (nt < 4) {
        Kr[(size_t)m * 64 + j] = f2bf(v + bk[j]);
      } else if (WRITE_Q && nt < 8) {
        Qs[(size_t)m * 64 + (j - 64)] = f2bf((v + bq[j - 64]) * QSCALE);
      } else {
        int h = j - (WRITE_Q ? 128 : 64);
        int bb = m >> 12, t = m & 4095;
        Vt[((size_t)(bb * 64 + h)) * 4096 + t] = f2bf(v + bv[h]);
      }
    }
  }
}

__global__ __launch_bounds__(256) void attnB_kernel(
    const unsigned short* __restrict__ Kr,
    const unsigned short* __restrict__ Vt,
    const float* __restrict__ X, const float* __restrict__ Wq,
    const float* __restrict__ bq, float* __restrict__ out) {
  __shared__ __align__(16) unsigned short Kl[64 * 72];
  __shared__ __align__(16) unsigned short Vl[64 * 72];
  __shared__ __align__(16) unsigned short Pl[4 * 16 * 72];
  const int tid = threadIdx.x;
  const int w   = tid >> 6;
  const int ln  = tid & 63;
  const int l15 = ln & 15;
  const int l4  = ln >> 4;
  const int b   = blockIdx.y;
  const int q0  = blockIdx.x * 64;
  const int qrow = q0 + w * 16;
  const f32x4 zero4 = {0.f, 0.f, 0.f, 0.f};
  unsigned short* Pw = &Pl[w * 16 * 72];
  f32x4 accq[4];
  #pragma unroll
  for (int i = 0; i < 4; ++i) accq[i] = zero4;
  const int wn = tid & 63;
  const int wk = (tid >> 6) * 16;
  for (int kb = 0; kb < 16; ++kb) {
    __syncthreads();
    #pragma unroll
    for (int p = 0; p < 4; ++p) {
      int chunk = tid + p * 256;
      int r = chunk >> 4, c4 = chunk & 15;
      const float4 xv = *reinterpret_cast<const float4*>(
          X + ((size_t)b * 4096 + q0 + r) * 1024 + kb * 64 + c4 * 4);
      bf16x4 o;
      o[0] = (short)f2bf(xv.x); o[1] = (short)f2bf(xv.y);
      o[2] = (short)f2bf(xv.z); o[3] = (short)f2bf(xv.w);
      *reinterpret_cast<bf16x4*>(&Kl[r * 72 + c4 * 4]) = o;
    }
    bf16x8 w0, w1;
    #pragma unroll
    for (int j = 0; j < 8; ++j)
      w0[j] = (short)f2bf(Wq[(size_t)(kb * 64 + wk + j) * 64 + wn]);
    #pragma unroll
    for (int j = 0; j < 8; ++j)
      w1[j] = (short)f2bf(Wq[(size_t)(kb * 64 + wk + 8 + j) * 64 + wn]);
    *reinterpret_cast<bf16x8*>(&Vl[wn * 72 + wk])     = w0;
    *reinterpret_cast<bf16x8*>(&Vl[wn * 72 + wk + 8]) = w1;
    __syncthreads();
    bf16x8 a0 = *reinterpret_cast<const bf16x8*>(&Kl[(w * 16 + l15) * 72 + l4 * 8]);
    bf16x8 a1 = *reinterpret_cast<const bf16x8*>(&Kl[(w * 16 + l15) * 72 + 32 + l4 * 8]);
    #pragma unroll
    for (int nt = 0; nt < 4; ++nt) {
      bf16x8 b0 = *reinterpret_cast<const bf16x8*>(&Vl[(nt * 16 + l15) * 72 + l4 * 8]);
      bf16x8 b1 = *reinterpret_cast<const bf16x8*>(&Vl[(nt * 16 + l15) * 72 + 32 + l4 * 8]);
      accq[nt] = __builtin_amdgcn_mfma_f32_16x16x32_bf16(a0, b0, accq[nt], 0, 0, 0);
      accq[nt] = __builtin_amdgcn_mfma_f32_16x16x32_bf16(a1, b1, accq[nt], 0, 0, 0);
    }
  }
  #pragma unroll
  for (int nt = 0; nt < 4; ++nt) {
    int h = nt * 16 + l15;
    #pragma unroll
    for (int r = 0; r < 4; ++r)
      Pw[(l4 * 4 + r) * 72 + h] = f2bf((accq[nt][r] + bq[h]) * 0.125f);
  }
  asm volatile("s_waitcnt lgkmcnt(0)" ::: "memory");
  __builtin_amdgcn_sched_barrier(0);
  bf16x8 qa0 = *reinterpret_cast<const bf16x8*>(&Pw[l15 * 72 + l4 * 8]);
  bf16x8 qa1 = *reinterpret_cast<const bf16x8*>(&Pw[l15 * 72 + 32 + l4 * 8]);
  f32x4 acco[4];
  #pragma unroll
  for (int i = 0; i < 4; ++i) acco[i] = zero4;
  float mrow[4] = {-1e30f, -1e30f, -1e30f, -1e30f};
  float lrow[4] = {0.f, 0.f, 0.f, 0.f};
  const int ktmax = blockIdx.x;
  for (int kt = 0; kt <= ktmax; ++kt) {
    const int kv0 = kt * 64;
    __syncthreads();
    #pragma unroll
    for (int p = 0; p < 2; ++p) {
      int chunk = tid + p * 256;
      int r = chunk >> 3, c8 = chunk & 7;
      *reinterpret_cast<bf16x8*>(&Kl[r * 72 + c8 * 8]) =
          *reinterpret_cast<const bf16x8*>(Kr + ((size_t)b * 4096 + kv0 + r) * 64 + c8 * 8);
      *reinterpret_cast<bf16x8*>(&Vl[r * 72 + c8 * 8]) =
          *reinterpret_cast<const bf16x8*>(Vt + ((size_t)b * 64 + r) * 4096 + kv0 + c8 * 8);
    }
    __syncthreads();
    f32x4 s[4];
    #pragma unroll
    for (int i = 0; i < 4; ++i) s[i] = zero4;
    #pragma unroll
    for (int nt = 0; nt < 4; ++nt) {
      bf16x8 k0 = *reinterpret_cast<const bf16x8*>(&Kl[(nt * 16 + l15) * 72 + l4 * 8]);
      bf16x8 k1 = *reinterpret_cast<const bf16x8*>(&Kl[(nt * 16 + l15) * 72 + 32 + l4 * 8]);
      s[nt] = __builtin_amdgcn_mfma_f32_16x16x32_bf16(qa0, k0, s[nt], 0, 0, 0);
      s[nt] = __builtin_amdgcn_mfma_f32_16x16x32_bf16(qa1, k1, s[nt], 0, 0, 0);
    }
    if (kt == ktmax) {
      #pragma unroll
      for (int nt = 0; nt < 4; ++nt) {
        int kv_g = kv0 + nt * 16 + l15;
        #pragma unroll
        for (int r = 0; r < 4; ++r) {
          int q_g = qrow + l4 * 4 + r;
          if (kv_g > q_g) s[nt][r] = -1e30f;
        }
      }
    }
    #pragma unroll
    for (int r = 0; r < 4; ++r) {
      float t = fmaxf(fmaxf(s[0][r], s[1][r]), fmaxf(s[2][r], s[3][r]));
      t = fmaxf(t, __shfl_xor(t, 1));
      t = fmaxf(t, __shfl_xor(t, 2));
      t = fmaxf(t, __shfl_xor(t, 4));
      t = fmaxf(t, __shfl_xor(t, 8));
      float mnew = fmaxf(mrow[r], t);
      float cc = __expf(mrow[r] - mnew);
      mrow[r] = mnew;
      lrow[r] *= cc;
      acco[0][r] *= cc; acco[1][r] *= cc; acco[2][r] *= cc; acco[3][r] *= cc;
    }
    #pragma unroll
    for (int nt = 0; nt < 4; ++nt) {
      #pragma unroll
      for (int r = 0; r < 4; ++r) {
        float p = __expf(s[nt][r] - mrow[r]);
        s[nt][r] = p;
        Pw[(l4 * 4 + r) * 72 + nt * 16 + l15] = f2bf(p);
      }
    }
    #pragma unroll
    for (int r = 0; r < 4; ++r) {
      float t = s[0][r] + s[1][r] + s[2][r] + s[3][r];
      t += __shfl_xor(t, 1);
      t += __shfl_xor(t, 2);
      t += __shfl_xor(t, 4);
      t += __shfl_xor(t, 8);
      lrow[r] += t;
    }
    asm volatile("s_waitcnt lgkmcnt(0)" ::: "memory");
    __builtin_amdgcn_sched_barrier(0);
    #pragma unroll
    for (int ks = 0; ks < 2; ++ks) {
      bf16x8 pa = *reinterpret_cast<const bf16x8*>(&Pw[l15 * 72 + ks * 32 + l4 * 8]);
      #pragma unroll
      for (int ht = 0; ht < 4; ++ht) {
        bf16x8 vf = *reinterpret_cast<const bf16x8*>(&Vl[(ht * 16 + l15) * 72 + ks * 32 + l4 * 8]);
        acco[ht] = __builtin_amdgcn_mfma_f32_16x16x32_bf16(pa, vf, acco[ht], 0, 0, 0);
      }
    }
  }
  float* ob = out + ((size_t)b * 4096 + qrow) * 64;
  #pragma unroll
  for (int ht = 0; ht < 4; ++ht) {
    #pragma unroll
    for (int r = 0; r < 4; ++r) {
      ob[(l4 * 4 + r) * 64 + ht * 16 + l15] = acco[ht][r] / lrow[r];
    }
  }
}

extern "C" void kernel_launch(void* const* d_in, const int* in_sizes, int n_in,
                              void* d_out, int out_size, void* d_ws, size_t ws_size,
                              hipStream_t stream) {
  const float* X  = (const float*)d_in[0];
  const float* Wk = (const float*)d_in[1];
  const float* bk = (const float*)d_in[2];
  const float* Wq = (const float*)d_in[3];
  const float* bq = (const float*)d_in[4];
  const float* Wv = (const float*)d_in[5];
  const float* bv = (const float*)d_in[6];
  float* out = (float*)d_out;

  char* ws = (char*)d_ws;
  const size_t SZ = 2097152;  // one bf16 [B*T][64] buffer
  unsigned short* Kr = (unsigned short*)(ws);
  unsigned short* Vt = (unsigned short*)(ws + SZ);

  if (ws_size >= 3 * SZ) {
    unsigned short* Qs = (unsigned short*)(ws + 2 * SZ);
    proj3_kernel<<<512, 256, 0, stream>>>(X, Wk, Wq, Wv, bk, bq, bv, Kr, Qs, Vt);
    attn5_kernel<<<512, 256, 0, stream>>>(Qs, Kr, Vt, out);
  } else {
    proj_kernel<false><<<256, 256, 0, stream>>>(X, Wk, Wq, Wv, bk, bq, bv, Kr, nullptr, Vt);
    attnB_kernel<<<dim3(64, 4), 256, 0, stream>>>(Kr, Vt, X, Wq, bq, out);
  }
}

// Round 8
// 91.171 us; speedup vs baseline: 1.1560x; 1.1560x over previous
//
#include <hip/hip_runtime.h>

// AttentionHead: B=4, T=4096, C=1024, H=64, causal softmax(QK^T/8)V
// R8: attn6 = per-wave-private K LDS pipeline (gll dbuf, swizzled, ZERO
// in-loop barriers, per-wave vmcnt only) + V direct-L2 early-issue +
// swapped QK^T + P-in-regs PV + kv-split-4 + exact 4-way merge.
// proj4 = proj2 (256 blk x 512 thr) + X register prefetch.

using bf16x8 = __attribute__((ext_vector_type(8))) short;
using bf16x4 = __attribute__((ext_vector_type(4))) short;
using f32x4  = __attribute__((ext_vector_type(4))) float;

#define QSCALE 0.1803368867f  // 0.125 * log2(e): softmax in exp2 domain

__device__ __forceinline__ unsigned short f2bf(float f) {
  union { float f; unsigned int u; } v; v.f = f;
  unsigned int r = v.u + 0x7fffu + ((v.u >> 16) & 1u);  // RNE
  return (unsigned short)(r >> 16);
}

__device__ __forceinline__ float fexp2(float x) {
#if __has_builtin(__builtin_amdgcn_exp2f)
  return __builtin_amdgcn_exp2f(x);
#else
  float r; asm("v_exp_f32 %0, %1" : "=v"(r) : "v"(x)); return r;
#endif
}

__device__ __forceinline__ void gl_lds16(const void* g, void* l) {
  __builtin_amdgcn_global_load_lds(
      (const __attribute__((address_space(1))) void*)g,
      (__attribute__((address_space(3))) void*)l, 16, 0, 0);
}

__device__ __forceinline__ f32x4 mfma16(bf16x4 a, bf16x4 b, f32x4 c) {
#if __has_builtin(__builtin_amdgcn_mfma_f32_16x16x16bf16_1k)
  return __builtin_amdgcn_mfma_f32_16x16x16bf16_1k(a, b, c, 0, 0, 0);
#else
  f32x4 d;
  asm volatile("v_mfma_f32_16x16x16_bf16 %0, %1, %2, %3"
               : "=v"(d) : "v"(a), "v"(b), "v"(c));
  return d;
#endif
}

// ---- proj4: 256 blocks x 512 thr; 64 rows x 192 cols; X reg prefetch --
__global__ __launch_bounds__(512) void proj4_kernel(
    const float* __restrict__ X,  const float* __restrict__ Wk,
    const float* __restrict__ Wq, const float* __restrict__ Wv,
    const float* __restrict__ bk, const float* __restrict__ bq,
    const float* __restrict__ bv, unsigned short* __restrict__ Kr,
    unsigned short* __restrict__ Qs, unsigned short* __restrict__ Vt) {
  __shared__ __align__(16) unsigned short Xl[64 * 72];
  __shared__ __align__(16) unsigned short Wl[192 * 72];
  const int tid = threadIdx.x;
  const int m0  = blockIdx.x * 64;
  const int w   = tid >> 6;      // 0..7
  const int mt  = w & 3;         // m-tile (16 rows)
  const int nh  = w >> 2;        // n-half (96 cols)
  const int ln  = tid & 63;
  const int l15 = ln & 15;
  const int l4  = ln >> 4;
  const int wn  = tid & 63;      // W staging: lane = n (coalesced)
  const int wk8 = (tid >> 6) * 8;
  const int xr0 = tid >> 4,          xc0 = tid & 15;
  const int xr1 = (tid + 512) >> 4,  xc1 = tid & 15;
  const f32x4 zero4 = {0.f, 0.f, 0.f, 0.f};

  f32x4 acc[6];
  #pragma unroll
  for (int i = 0; i < 6; ++i) acc[i] = zero4;

  float4 xp0 = *reinterpret_cast<const float4*>(X + (size_t)(m0 + xr0) * 1024 + xc0 * 4);
  float4 xp1 = *reinterpret_cast<const float4*>(X + (size_t)(m0 + xr1) * 1024 + xc1 * 4);

  for (int kb = 0; kb < 16; ++kb) {
    __syncthreads();
    // write prefetched X tile (fp32 -> bf16)
    bf16x4 o0, o1;
    o0[0] = (short)f2bf(xp0.x); o0[1] = (short)f2bf(xp0.y);
    o0[2] = (short)f2bf(xp0.z); o0[3] = (short)f2bf(xp0.w);
    o1[0] = (short)f2bf(xp1.x); o1[1] = (short)f2bf(xp1.y);
    o1[2] = (short)f2bf(xp1.z); o1[3] = (short)f2bf(xp1.w);
    *reinterpret_cast<bf16x4*>(&Xl[xr0 * 72 + xc0 * 4]) = o0;
    *reinterpret_cast<bf16x4*>(&Xl[xr1 * 72 + xc1 * 4]) = o1;
    if (kb < 15) {  // prefetch next X (HBM latency over W-stage+MFMA)
      xp0 = *reinterpret_cast<const float4*>(
          X + (size_t)(m0 + xr0) * 1024 + (kb + 1) * 64 + xc0 * 4);
      xp1 = *reinterpret_cast<const float4*>(
          X + (size_t)(m0 + xr1) * 1024 + (kb + 1) * 64 + xc1 * 4);
    }
    // stage W transposed (L2-resident)
    #pragma unroll
    for (int c = 0; c < 3; ++c) {
      const float* Wsrc = (c == 0) ? Wk : ((c == 1) ? Wq : Wv);
      bf16x8 w0;
      #pragma unroll
      for (int j = 0; j < 8; ++j)
        w0[j] = (short)f2bf(Wsrc[(size_t)(kb * 64 + wk8 + j) * 64 + wn]);
      *reinterpret_cast<bf16x8*>(&Wl[(c * 64 + wn) * 72 + wk8]) = w0;
    }
    __syncthreads();
    bf16x8 a0 = *reinterpret_cast<const bf16x8*>(&Xl[(mt * 16 + l15) * 72 + l4 * 8]);
    bf16x8 a1 = *reinterpret_cast<const bf16x8*>(&Xl[(mt * 16 + l15) * 72 + 32 + l4 * 8]);
    #pragma unroll
    for (int i = 0; i < 6; ++i) {
      int row = nh * 96 + i * 16 + l15;
      bf16x8 b0 = *reinterpret_cast<const bf16x8*>(&Wl[row * 72 + l4 * 8]);
      bf16x8 b1 = *reinterpret_cast<const bf16x8*>(&Wl[row * 72 + 32 + l4 * 8]);
      acc[i] = __builtin_amdgcn_mfma_f32_16x16x32_bf16(a0, b0, acc[i], 0, 0, 0);
      acc[i] = __builtin_amdgcn_mfma_f32_16x16x32_bf16(a1, b1, acc[i], 0, 0, 0);
    }
  }
  #pragma unroll
  for (int i = 0; i < 6; ++i) {
    int j = nh * 96 + i * 16 + l15;
    int mr0 = m0 + mt * 16 + l4 * 4;
    if (j < 64) {
      #pragma unroll
      for (int r = 0; r < 4; ++r)
        Kr[(size_t)(mr0 + r) * 64 + j] = f2bf(acc[i][r] + bk[j]);
    } else if (j < 128) {
      int jq = j - 64;
      #pragma unroll
      for (int r = 0; r < 4; ++r)
        Qs[(size_t)(mr0 + r) * 64 + jq] = f2bf((acc[i][r] + bq[jq]) * QSCALE);
    } else {
      int h = j - 128;
      int bb = mr0 >> 12, t0 = mr0 & 4095;
      ushort4 o;
      o.x = f2bf(acc[i][0] + bv[h]); o.y = f2bf(acc[i][1] + bv[h]);
      o.z = f2bf(acc[i][2] + bv[h]); o.w = f2bf(acc[i][3] + bv[h]);
      *reinterpret_cast<ushort4*>(&Vt[((size_t)(bb * 64 + h)) * 4096 + t0]) = o;
    }
  }
}

// ---- attn6: per-wave K LDS pipeline, no in-loop barriers --------------
__global__ __launch_bounds__(256) void attn6_kernel(
    const unsigned short* __restrict__ Qs,
    const unsigned short* __restrict__ Kr,
    const unsigned short* __restrict__ Vt,
    float* __restrict__ out) {
  __shared__ __align__(16) unsigned short Klds[4][2][64 * 64];  // 64KB
  const int tid = threadIdx.x;
  const int w   = tid >> 6;            // kv residue class
  const int ln  = tid & 63;
  const int l15 = ln & 15;
  const int l4  = ln >> 4;
  const int bid = blockIdx.x;
  const int qt  = 127 - (bid >> 2);    // longest-first
  const int b   = bid & 3;             // batch pinned per XCD pair
  const int qbase  = qt * 32;
  const int ntiles = (qt >> 1) + 1;    // 64-kv tiles
  const f32x4 zero4 = {0.f, 0.f, 0.f, 0.f};

  const int lswz16 = (ln ^ (ln >> 3)) * 16;   // gll source swizzle
  const char* Kbase = (const char*)Kr + (size_t)b * 4096 * 128;

  // Q fragments for both 16-row halves (B-operand: n=q=l15, k=h)
  const unsigned short* Q0 = Qs + ((size_t)b * 4096 + qbase + l15) * 64;
  const bf16x8 qa0 = *reinterpret_cast<const bf16x8*>(Q0 + l4 * 8);
  const bf16x8 qa1 = *reinterpret_cast<const bf16x8*>(Q0 + 32 + l4 * 8);
  const bf16x8 qb0 = *reinterpret_cast<const bf16x8*>(Q0 + 1024 + l4 * 8);
  const bf16x8 qb1 = *reinterpret_cast<const bf16x8*>(Q0 + 1024 + 32 + l4 * 8);

  // V^T row pointers (A-frag per ht: row h=ht*16+l15, k=4*l4+i)
  const unsigned short* Vh0 = Vt + ((size_t)(b * 64) + l15) * 4096 + l4 * 4;
  const unsigned short* Vh1 = Vh0 + 16 * 4096;
  const unsigned short* Vh2 = Vh0 + 32 * 4096;
  const unsigned short* Vh3 = Vh0 + 48 * 4096;

  f32x4 accA[4], accB[4];
  #pragma unroll
  for (int i = 0; i < 4; ++i) { accA[i] = zero4; accB[i] = zero4; }
  float mA = -1e30f, lA = 0.f, mB = -1e30f, lB = 0.f;

  auto stageK = [&](int buf, int t) {
    const char* src = Kbase + (size_t)t * 8192 + lswz16;
    char* dst = (char*)&Klds[w][buf][0];
    #pragma unroll
    for (int j = 0; j < 8; ++j)
      gl_lds16(src + j * 1024, dst + j * 1024);
  };

  int cur = 0;
  if (w < ntiles) stageK(0, w);
  asm volatile("s_waitcnt vmcnt(0)" ::: "memory");   // own-wave gll: no barrier

  for (int t = w; t < ntiles; t += 4) {
    // V loads for tile t first (L2 latency covered by QK^T + softmax)
    const int toff = t * 64;
    bf16x4 vf0[4], vf1[4], vf2[4], vf3[4];
    #pragma unroll
    for (int nt = 0; nt < 4; ++nt) {
      vf0[nt] = *reinterpret_cast<const bf16x4*>(Vh0 + toff + nt * 16);
      vf1[nt] = *reinterpret_cast<const bf16x4*>(Vh1 + toff + nt * 16);
      vf2[nt] = *reinterpret_cast<const bf16x4*>(Vh2 + toff + nt * 16);
      vf3[nt] = *reinterpret_cast<const bf16x4*>(Vh3 + toff + nt * 16);
    }
    const bool haveNext = (t + 4 < ntiles);
    if (haveNext) stageK(cur ^ 1, t + 4);  // prefetch next K tile

    // ---- S^T = K Q^T from swizzled LDS
    f32x4 sA[4], sB[4];
    #pragma unroll
    for (int i = 0; i < 4; ++i) { sA[i] = zero4; sB[i] = zero4; }
    __builtin_amdgcn_s_setprio(1);
    #pragma unroll
    for (int nt = 0; nt < 4; ++nt) {
      const int krow = nt * 16 + l15;
      const unsigned short* kp = &Klds[w][cur][krow * 64];
      bf16x8 k0 = *reinterpret_cast<const bf16x8*>(kp + ((l4 ^ (krow & 7)) << 3));
      bf16x8 k1 = *reinterpret_cast<const bf16x8*>(kp + (((l4 + 4) ^ (krow & 7)) << 3));
      sA[nt] = __builtin_amdgcn_mfma_f32_16x16x32_bf16(k0, qa0, sA[nt], 0, 0, 0);
      sA[nt] = __builtin_amdgcn_mfma_f32_16x16x32_bf16(k1, qa1, sA[nt], 0, 0, 0);
      sB[nt] = __builtin_amdgcn_mfma_f32_16x16x32_bf16(k0, qb0, sB[nt], 0, 0, 0);
      sB[nt] = __builtin_amdgcn_mfma_f32_16x16x32_bf16(k1, qb1, sB[nt], 0, 0, 0);
    }
    __builtin_amdgcn_s_setprio(0);

    if (t == ntiles - 1) {  // causal mask (only last tile crosses diagonal)
      const int qmA = qbase + l15 - toff;
      #pragma unroll
      for (int nt = 0; nt < 4; ++nt)
        #pragma unroll
        for (int r = 0; r < 4; ++r) {
          int kvl = nt * 16 + 4 * l4 + r;
          if (kvl > qmA)      sA[nt][r] = -1e30f;
          if (kvl > qmA + 16) sB[nt][r] = -1e30f;
        }
    }

    // ---- online softmax (lane-local 16 + 2 shfls), halves A and B
    bf16x4 paA[4], paB[4];
    {
      float x0 = fmaxf(fmaxf(sA[0][0], sA[0][1]), fmaxf(sA[0][2], sA[0][3]));
      float x1 = fmaxf(fmaxf(sA[1][0], sA[1][1]), fmaxf(sA[1][2], sA[1][3]));
      float x2 = fmaxf(fmaxf(sA[2][0], sA[2][1]), fmaxf(sA[2][2], sA[2][3]));
      float x3 = fmaxf(fmaxf(sA[3][0], sA[3][1]), fmaxf(sA[3][2], sA[3][3]));
      float xm = fmaxf(fmaxf(x0, x1), fmaxf(x2, x3));
      xm = fmaxf(xm, __shfl_xor(xm, 16));
      xm = fmaxf(xm, __shfl_xor(xm, 32));
      float mn = fmaxf(mA, xm);
      float cc = fexp2(mA - mn);
      mA = mn; lA *= cc;
      #pragma unroll
      for (int ht = 0; ht < 4; ++ht)
        #pragma unroll
        for (int r = 0; r < 4; ++r) accA[ht][r] *= cc;
      float sum = 0.f;
      #pragma unroll
      for (int nt = 0; nt < 4; ++nt) {
        #pragma unroll
        for (int r = 0; r < 4; ++r) {
          float p = fexp2(sA[nt][r] - mA);
          sA[nt][r] = p;
          paA[nt][r] = (short)f2bf(p);
        }
        sum += (sA[nt][0] + sA[nt][1]) + (sA[nt][2] + sA[nt][3]);
      }
      sum += __shfl_xor(sum, 16);
      sum += __shfl_xor(sum, 32);
      lA += sum;
    }
    {
      float x0 = fmaxf(fmaxf(sB[0][0], sB[0][1]), fmaxf(sB[0][2], sB[0][3]));
      float x1 = fmaxf(fmaxf(sB[1][0], sB[1][1]), fmaxf(sB[1][2], sB[1][3]));
      float x2 = fmaxf(fmaxf(sB[2][0], sB[2][1]), fmaxf(sB[2][2], sB[2][3]));
      float x3 = fmaxf(fmaxf(sB[3][0], sB[3][1]), fmaxf(sB[3][2], sB[3][3]));
      float xm = fmaxf(fmaxf(x0, x1), fmaxf(x2, x3));
      xm = fmaxf(xm, __shfl_xor(xm, 16));
      xm = fmaxf(xm, __shfl_xor(xm, 32));
      float mn = fmaxf(mB, xm);
      float cc = fexp2(mB - mn);
      mB = mn; lB *= cc;
      #pragma unroll
      for (int ht = 0; ht < 4; ++ht)
        #pragma unroll
        for (int r = 0; r < 4; ++r) accB[ht][r] *= cc;
      float sum = 0.f;
      #pragma unroll
      for (int nt = 0; nt < 4; ++nt) {
        #pragma unroll
        for (int r = 0; r < 4; ++r) {
          float p = fexp2(sB[nt][r] - mB);
          sB[nt][r] = p;
          paB[nt][r] = (short)f2bf(p);
        }
        sum += (sB[nt][0] + sB[nt][1]) + (sB[nt][2] + sB[nt][3]);
      }
      sum += __shfl_xor(sum, 16);
      sum += __shfl_xor(sum, 32);
      lB += sum;
    }

    // ---- O^T += V^T P^T (compiler auto-waits vf)
    __builtin_amdgcn_s_setprio(1);
    #pragma unroll
    for (int nt = 0; nt < 4; ++nt) {
      accA[0] = mfma16(vf0[nt], paA[nt], accA[0]);
      accA[1] = mfma16(vf1[nt], paA[nt], accA[1]);
      accA[2] = mfma16(vf2[nt], paA[nt], accA[2]);
      accA[3] = mfma16(vf3[nt], paA[nt], accA[3]);
      accB[0] = mfma16(vf0[nt], paB[nt], accB[0]);
      accB[1] = mfma16(vf1[nt], paB[nt], accB[1]);
      accB[2] = mfma16(vf2[nt], paB[nt], accB[2]);
      accB[3] = mfma16(vf3[nt], paB[nt], accB[3]);
    }
    __builtin_amdgcn_s_setprio(0);

    if (haveNext) {  // next K tile landed (own-wave gll, had ~full iter)
      asm volatile("s_waitcnt vmcnt(0)" ::: "memory");
      cur ^= 1;
    }
  }

  // ---- exact 4-way merge; alias Klds after all compute done ----------
  __syncthreads();
  float* MOb = (float*)&Klds[0][0][0];      // [3][2][16][68] f32
  float* MLb = MOb + 3 * 2 * 16 * 68;       // [3][2][2][16]  f32
  if (w > 0) {
    const int p = w - 1;
    #pragma unroll
    for (int ht = 0; ht < 4; ++ht) {
      *reinterpret_cast<f32x4*>(&MOb[((p * 2 + 0) * 16 + l15) * 68 + ht * 16 + 4 * l4]) = accA[ht];
      *reinterpret_cast<f32x4*>(&MOb[((p * 2 + 1) * 16 + l15) * 68 + ht * 16 + 4 * l4]) = accB[ht];
    }
    if (l4 == 0) {
      MLb[((p * 2 + 0) * 2 + 0) * 16 + l15] = mA;
      MLb[((p * 2 + 0) * 2 + 1) * 16 + l15] = lA;
      MLb[((p * 2 + 1) * 2 + 0) * 16 + l15] = mB;
      MLb[((p * 2 + 1) * 2 + 1) * 16 + l15] = lB;
    }
  }
  __syncthreads();
  if (w == 0) {
    #pragma unroll
    for (int hf = 0; hf < 2; ++hf) {
      float m = hf ? mB : mA;
      float l = hf ? lB : lA;
      float m0_ = MLb[((0 * 2 + hf) * 2 + 0) * 16 + l15];
      float m1_ = MLb[((1 * 2 + hf) * 2 + 0) * 16 + l15];
      float m2_ = MLb[((2 * 2 + hf) * 2 + 0) * 16 + l15];
      float mM = fmaxf(fmaxf(m, m0_), fmaxf(m1_, m2_));
      float aS = fexp2(m - mM);
      float a0 = fexp2(m0_ - mM), a1 = fexp2(m1_ - mM), a2 = fexp2(m2_ - mM);
      float lT = l * aS + MLb[((0 * 2 + hf) * 2 + 1) * 16 + l15] * a0
               + MLb[((1 * 2 + hf) * 2 + 1) * 16 + l15] * a1
               + MLb[((2 * 2 + hf) * 2 + 1) * 16 + l15] * a2;
      float linv = 1.0f / lT;
      float* ob = out + ((size_t)b * 4096 + qbase + hf * 16 + l15) * 64;
      #pragma unroll
      for (int ht = 0; ht < 4; ++ht) {
        f32x4 ac = hf ? accB[ht] : accA[ht];
        f32x4 o0 = *reinterpret_cast<const f32x4*>(&MOb[((0 * 2 + hf) * 16 + l15) * 68 + ht * 16 + 4 * l4]);
        f32x4 o1 = *reinterpret_cast<const f32x4*>(&MOb[((1 * 2 + hf) * 16 + l15) * 68 + ht * 16 + 4 * l4]);
        f32x4 o2 = *reinterpret_cast<const f32x4*>(&MOb[((2 * 2 + hf) * 16 + l15) * 68 + ht * 16 + 4 * l4]);
        float4 o;
        o.x = (ac[0] * aS + o0[0] * a0 + o1[0] * a1 + o2[0] * a2) * linv;
        o.y = (ac[1] * aS + o0[1] * a0 + o1[1] * a1 + o2[1] * a2) * linv;
        o.z = (ac[2] * aS + o0[2] * a0 + o1[2] * a1 + o2[2] * a2) * linv;
        o.w = (ac[3] * aS + o0[3] * a0 + o1[3] * a1 + o2[3] * a2) * linv;
        *reinterpret_cast<float4*>(ob + ht * 16 + 4 * l4) = o;
      }
    }
  }
}

// ---- Plan-B fallback: old proj (no Q) + attn with Q recompute ---------
template <bool WRITE_Q>
__global__ __launch_bounds__(256) void proj_kernel(
    const float* __restrict__ X,  const float* __restrict__ Wk,
    const float* __restrict__ Wq, const float* __restrict__ Wv,
    const float* __restrict__ bk, const float* __restrict__ bq,
    const float* __restrict__ bv, unsigned short* __restrict__ Kr,
    unsigned short* __restrict__ Qs, unsigned short* __restrict__ Vt) {
  constexpr int NT = WRITE_Q ? 12 : 8;
  constexpr int NC = NT / 4;
  __shared__ __align__(16) unsigned short Xl[64 * 72];
  __shared__ __align__(16) unsigned short Wl[NT * 16 * 72];
  const int tid = threadIdx.x;
  const int m0  = blockIdx.x * 64;
  const int w   = tid >> 6;
  const int ln  = tid & 63;
  const int l15 = ln & 15;
  const int l4  = ln >> 4;
  const f32x4 zero4 = {0.f, 0.f, 0.f, 0.f};
  f32x4 acc[NT];
  #pragma unroll
  for (int i = 0; i < NT; ++i) acc[i] = zero4;
  const int wn = tid & 63;
  const int wk = (tid >> 6) * 16;
  for (int kb = 0; kb < 16; ++kb) {
    __syncthreads();
    #pragma unroll
    for (int p = 0; p < 4; ++p) {
      int chunk = tid + p * 256;
      int r = chunk >> 4, c4 = chunk & 15;
      const float4 xv = *reinterpret_cast<const float4*>(
          X + (size_t)(m0 + r) * 1024 + kb * 64 + c4 * 4);
      bf16x4 o;
      o[0] = (short)f2bf(xv.x); o[1] = (short)f2bf(xv.y);
      o[2] = (short)f2bf(xv.z); o[3] = (short)f2bf(xv.w);
      *reinterpret_cast<bf16x4*>(&Xl[r * 72 + c4 * 4]) = o;
    }
    #pragma unroll
    for (int c = 0; c < NC; ++c) {
      const float* Wsrc = (c == 0) ? Wk : ((WRITE_Q && c == 1) ? Wq : Wv);
      bf16x8 w0, w1;
      #pragma unroll
      for (int j = 0; j < 8; ++j)
        w0[j] = (short)f2bf(Wsrc[(size_t)(kb * 64 + wk + j) * 64 + wn]);
      #pragma unroll
      for (int j = 0; j < 8; ++j)
        w1[j] = (short)f2bf(Wsrc[(size_t)(kb * 64 + wk + 8 + j) * 64 + wn]);
      *reinterpret_cast<bf16x8*>(&Wl[(c * 64 + wn) * 72 + wk])     = w0;
      *reinterpret_cast<bf16x8*>(&Wl[(c * 64 + wn) * 72 + wk + 8]) = w1;
    }
    __syncthreads();
    bf16x8 a0 = *reinterpret_cast<const bf16x8*>(&Xl[(w * 16 + l15) * 72 + l4 * 8]);
    bf16x8 a1 = *reinterpret_cast<const bf16x8*>(&Xl[(w * 16 + l15) * 72 + 32 + l4 * 8]);
    #pragma unroll
    for (int nt = 0; nt < NT; ++nt) {
      bf16x8 b0 = *reinterpret_cast<const bf16x8*>(&Wl[(nt * 16 + l15) * 72 + l4 * 8]);
      bf16x8 b1 = *reinterpret_cast<const bf16x8*>(&Wl[(nt * 16 + l15) * 72 + 32 + l4 * 8]);
      acc[nt] = __builtin_amdgcn_mfma_f32_16x16x32_bf16(a0, b0, acc[nt], 0, 0, 0);
      acc[nt] = __builtin_amdgcn_mfma_f32_16x16x32_bf16(a1, b1, acc[nt], 0, 0, 0);
    }
  }
  #pragma unroll
  for (int nt = 0; nt < NT; ++nt) {
    int j = nt * 16 + l15;
    #pragma unroll
    for (int r = 0; r < 4; ++r) {
      int m = m0 + w * 16 + l4 * 4 + r;
      float v = acc[nt][r];
      if (nt < 4) {
        Kr[(size_t)m * 64 + j] = f2bf(v + bk[j]);
      } else if (WRITE_Q && nt < 8) {
        Qs[(size_t)m * 64 + (j - 64)] = f2bf((v + bq[j - 64]) * QSCALE);
      } else {
        int h = j - (WRITE_Q ? 128 : 64);
        int bb = m >> 12, t = m & 4095;
        Vt[((size_t)(bb * 64 + h)) * 4096 + t] = f2bf(v + bv[h]);
      }
    }
  }
}

__global__ __launch_bounds__(256) void attnB_kernel(
    const unsigned short* __restrict__ Kr,
    const unsigned short* __restrict__ Vt,
    const float* __restrict__ X, const float* __restrict__ Wq,
    const float* __restrict__ bq, float* __restrict__ out) {
  __shared__ __align__(16) unsigned short Kl[64 * 72];
  __shared__ __align__(16) unsigned short Vl[64 * 72];
  __shared__ __align__(16) unsigned short Pl[4 * 16 * 72];
  const int tid = threadIdx.x;
  const int w   = tid >> 6;
  const int ln  = tid & 63;
  const int l15 = ln & 15;
  const int l4  = ln >> 4;
  const int b   = blockIdx.y;
  const int q0  = blockIdx.x * 64;
  const int qrow = q0 + w * 16;
  const f32x4 zero4 = {0.f, 0.f, 0.f, 0.f};
  unsigned short* Pw = &Pl[w * 16 * 72];
  f32x4 accq[4];
  #pragma unroll
  for (int i = 0; i < 4; ++i) accq[i] = zero4;
  const int wn = tid & 63;
  const int wk = (tid >> 6) * 16;
  for (int kb = 0; kb < 16; ++kb) {
    __syncthreads();
    #pragma unroll
    for (int p = 0; p < 4; ++p) {
      int chunk = tid + p * 256;
      int r = chunk >> 4, c4 = chunk & 15;
      const float4 xv = *reinterpret_cast<const float4*>(
          X + ((size_t)b * 4096 + q0 + r) * 1024 + kb * 64 + c4 * 4);
      bf16x4 o;
      o[0] = (short)f2bf(xv.x); o[1] = (short)f2bf(xv.y);
      o[2] = (short)f2bf(xv.z); o[3] = (short)f2bf(xv.w);
      *reinterpret_cast<bf16x4*>(&Kl[r * 72 + c4 * 4]) = o;
    }
    bf16x8 w0, w1;
    #pragma unroll
    for (int j = 0; j < 8; ++j)
      w0[j] = (short)f2bf(Wq[(size_t)(kb * 64 + wk + j) * 64 + wn]);
    #pragma unroll
    for (int j = 0; j < 8; ++j)
      w1[j] = (short)f2bf(Wq[(size_t)(kb * 64 + wk + 8 + j) * 64 + wn]);
    *reinterpret_cast<bf16x8*>(&Vl[wn * 72 + wk])     = w0;
    *reinterpret_cast<bf16x8*>(&Vl[wn * 72 + wk + 8]) = w1;
    __syncthreads();
    bf16x8 a0 = *reinterpret_cast<const bf16x8*>(&Kl[(w * 16 + l15) * 72 + l4 * 8]);
    bf16x8 a1 = *reinterpret_cast<const bf16x8*>(&Kl[(w * 16 + l15) * 72 + 32 + l4 * 8]);
    #pragma unroll
    for (int nt = 0; nt < 4; ++nt) {
      bf16x8 b0 = *reinterpret_cast<const bf16x8*>(&Vl[(nt * 16 + l15) * 72 + l4 * 8]);
      bf16x8 b1 = *reinterpret_cast<const bf16x8*>(&Vl[(nt * 16 + l15) * 72 + 32 + l4 * 8]);
      accq[nt] = __builtin_amdgcn_mfma_f32_16x16x32_bf16(a0, b0, accq[nt], 0, 0, 0);
      accq[nt] = __builtin_amdgcn_mfma_f32_16x16x32_bf16(a1, b1, accq[nt], 0, 0, 0);
    }
  }
  #pragma unroll
  for (int nt = 0; nt < 4; ++nt) {
    int h = nt * 16 + l15;
    #pragma unroll
    for (int r = 0; r < 4; ++r)
      Pw[(l4 * 4 + r) * 72 + h] = f2bf((accq[nt][r] + bq[h]) * 0.125f);
  }
  asm volatile("s_waitcnt lgkmcnt(0)" ::: "memory");
  __builtin_amdgcn_sched_barrier(0);
  bf16x8 qa0 = *reinterpret_cast<const bf16x8*>(&Pw[l15 * 72 + l4 * 8]);
  bf16x8 qa1 = *reinterpret_cast<const bf16x8*>(&Pw[l15 * 72 + 32 + l4 * 8]);
  f32x4 acco[4];
  #pragma unroll
  for (int i = 0; i < 4; ++i) acco[i] = zero4;
  float mrow[4] = {-1e30f, -1e30f, -1e30f, -1e30f};
  float lrow[4] = {0.f, 0.f, 0.f, 0.f};
  const int ktmax = blockIdx.x;
  for (int kt = 0; kt <= ktmax; ++kt) {
    const int kv0 = kt * 64;
    __syncthreads();
    #pragma unroll
    for (int p = 0; p < 2; ++p) {
      int chunk = tid + p * 256;
      int r = chunk >> 3, c8 = chunk & 7;
      *reinterpret_cast<bf16x8*>(&Kl[r * 72 + c8 * 8]) =
          *reinterpret_cast<const bf16x8*>(Kr + ((size_t)b * 4096 + kv0 + r) * 64 + c8 * 8);
      *reinterpret_cast<bf16x8*>(&Vl[r * 72 + c8 * 8]) =
          *reinterpret_cast<const bf16x8*>(Vt + ((size_t)b * 64 + r) * 4096 + kv0 + c8 * 8);
    }
    __syncthreads();
    f32x4 s[4];
    #pragma unroll
    for (int i = 0; i < 4; ++i) s[i] = zero4;
    #pragma unroll
    for (int nt = 0; nt < 4; ++nt) {
      bf16x8 k0 = *reinterpret_cast<const bf16x8*>(&Kl[(nt * 16 + l15) * 72 + l4 * 8]);
      bf16x8 k1 = *reinterpret_cast<const bf16x8*>(&Kl[(nt * 16 + l15) * 72 + 32 + l4 * 8]);
      s[nt] = __builtin_amdgcn_mfma_f32_16x16x32_bf16(qa0, k0, s[nt], 0, 0, 0);
      s[nt] = __builtin_amdgcn_mfma_f32_16x16x32_bf16(qa1, k1, s[nt], 0, 0, 0);
    }
    if (kt == ktmax) {
      #pragma unroll
      for (int nt = 0; nt < 4; ++nt) {
        int kv_g = kv0 + nt * 16 + l15;
        #pragma unroll
        for (int r = 0; r < 4; ++r) {
          int q_g = qrow + l4 * 4 + r;
          if (kv_g > q_g) s[nt][r] = -1e30f;
        }
      }
    }
    #pragma unroll
    for (int r = 0; r < 4; ++r) {
      float t = fmaxf(fmaxf(s[0][r], s[1][r]), fmaxf(s[2][r], s[3][r]));
      t = fmaxf(t, __shfl_xor(t, 1));
      t = fmaxf(t, __shfl_xor(t, 2));
      t = fmaxf(t, __shfl_xor(t, 4));
      t = fmaxf(t, __shfl_xor(t, 8));
      float mnew = fmaxf(mrow[r], t);
      float cc = __expf(mrow[r] - mnew);
      mrow[r] = mnew;
      lrow[r] *= cc;
      acco[0][r] *= cc; acco[1][r] *= cc; acco[2][r] *= cc; acco[3][r] *= cc;
    }
    #pragma unroll
    for (int nt = 0; nt < 4; ++nt) {
      #pragma unroll
      for (int r = 0; r < 4; ++r) {
        float p = __expf(s[nt][r] - mrow[r]);
        s[nt][r] = p;
        Pw[(l4 * 4 + r) * 72 + nt * 16 + l15] = f2bf(p);
      }
    }
    #pragma unroll
    for (int r = 0; r < 4; ++r) {
      float t = s[0][r] + s[1][r] + s[2][r] + s[3][r];
      t += __shfl_xor(t, 1);
      t += __shfl_xor(t, 2);
      t += __shfl_xor(t, 4);
      t += __shfl_xor(t, 8);
      lrow[r] += t;
    }
    asm volatile("s_waitcnt lgkmcnt(0)" ::: "memory");
    __builtin_amdgcn_sched_barrier(0);
    #pragma unroll
    for (int ks = 0; ks < 2; ++ks) {
      bf16x8 pa = *reinterpret_cast<const bf16x8*>(&Pw[l15 * 72 + ks * 32 + l4 * 8]);
      #pragma unroll
      for (int ht = 0; ht < 4; ++ht) {
        bf16x8 vf = *reinterpret_cast<const bf16x8*>(&Vl[(ht * 16 + l15) * 72 + ks * 32 + l4 * 8]);
        acco[ht] = __builtin_amdgcn_mfma_f32_16x16x32_bf16(pa, vf, acco[ht], 0, 0, 0);
      }
    }
  }
  float* ob = out + ((size_t)b * 4096 + qrow) * 64;
  #pragma unroll
  for (int ht = 0; ht < 4; ++ht) {
    #pragma unroll
    for (int r = 0; r < 4; ++r) {
      ob[(l4 * 4 + r) * 64 + ht * 16 + l15] = acco[ht][r] / lrow[r];
    }
  }
}

extern "C" void kernel_launch(void* const* d_in, const int* in_sizes, int n_in,
                              void* d_out, int out_size, void* d_ws, size_t ws_size,
                              hipStream_t stream) {
  const float* X  = (const float*)d_in[0];
  const float* Wk = (const float*)d_in[1];
  const float* bk = (const float*)d_in[2];
  const float* Wq = (const float*)d_in[3];
  const float* bq = (const float*)d_in[4];
  const float* Wv = (const float*)d_in[5];
  const float* bv = (const float*)d_in[6];
  float* out = (float*)d_out;

  char* ws = (char*)d_ws;
  const size_t SZ = 2097152;  // one bf16 [B*T][64] buffer
  unsigned short* Kr = (unsigned short*)(ws);
  unsigned short* Vt = (unsigned short*)(ws + SZ);

  if (ws_size >= 3 * SZ) {
    unsigned short* Qs = (unsigned short*)(ws + 2 * SZ);
    proj4_kernel<<<256, 512, 0, stream>>>(X, Wk, Wq, Wv, bk, bq, bv, Kr, Qs, Vt);
    attn6_kernel<<<512, 256, 0, stream>>>(Qs, Kr, Vt, out);
  } else {
    proj_kernel<false><<<256, 256, 0, stream>>>(X, Wk, Wq, Wv, bk, bq, bv, Kr, nullptr, Vt);
    attnB_kernel<<<dim3(64, 4), 256, 0, stream>>>(Kr, Vt, X, Wq, bq, out);
  }
}

// Round 10
// 79.176 us; speedup vs baseline: 1.3311x; 1.1515x over previous
//
#include <hip/hip_runtime.h>

// AttentionHead: B=4, T=4096, C=1024, H=64, causal softmax(QK^T/8)V
// R9 (resubmit after infra failure): attn7 = per-wave-private K(dbuf)+V
// LDS pipelines, ALL staging via coalesced global_load_lds (R8 lesson:
// per-lane fragment loads from L2 serialize 16 lines/instr). Zero in-loop
// barriers; counted vmcnt waits. kv-tile 32, kv-split-4, 512x4 waves,
// exact 4-way merge. proj4 unchanged (attribution).

using bf16x8 = __attribute__((ext_vector_type(8))) short;
using bf16x4 = __attribute__((ext_vector_type(4))) short;
using f32x4  = __attribute__((ext_vector_type(4))) float;

#define QSCALE 0.1803368867f  // 0.125 * log2(e): softmax in exp2 domain

__device__ __forceinline__ unsigned short f2bf(float f) {
  union { float f; unsigned int u; } v; v.f = f;
  unsigned int r = v.u + 0x7fffu + ((v.u >> 16) & 1u);  // RNE
  return (unsigned short)(r >> 16);
}

__device__ __forceinline__ float fexp2(float x) {
#if __has_builtin(__builtin_amdgcn_exp2f)
  return __builtin_amdgcn_exp2f(x);
#else
  float r; asm("v_exp_f32 %0, %1" : "=v"(r) : "v"(x)); return r;
#endif
}

__device__ __forceinline__ void gl_lds16(const void* g, void* l) {
  __builtin_amdgcn_global_load_lds(
      (const __attribute__((address_space(1))) void*)g,
      (__attribute__((address_space(3))) void*)l, 16, 0, 0);
}

__device__ __forceinline__ f32x4 mfma16(bf16x4 a, bf16x4 b, f32x4 c) {
#if __has_builtin(__builtin_amdgcn_mfma_f32_16x16x16bf16_1k)
  return __builtin_amdgcn_mfma_f32_16x16x16bf16_1k(a, b, c, 0, 0, 0);
#else
  f32x4 d;
  asm volatile("v_mfma_f32_16x16x16_bf16 %0, %1, %2, %3"
               : "=v"(d) : "v"(a), "v"(b), "v"(c));
  return d;
#endif
}

// ---- proj4: 256 blocks x 512 thr; 64 rows x 192 cols; X reg prefetch --
__global__ __launch_bounds__(512) void proj4_kernel(
    const float* __restrict__ X,  const float* __restrict__ Wk,
    const float* __restrict__ Wq, const float* __restrict__ Wv,
    const float* __restrict__ bk, const float* __restrict__ bq,
    const float* __restrict__ bv, unsigned short* __restrict__ Kr,
    unsigned short* __restrict__ Qs, unsigned short* __restrict__ Vt) {
  __shared__ __align__(16) unsigned short Xl[64 * 72];
  __shared__ __align__(16) unsigned short Wl[192 * 72];
  const int tid = threadIdx.x;
  const int m0  = blockIdx.x * 64;
  const int w   = tid >> 6;
  const int mt  = w & 3;
  const int nh  = w >> 2;
  const int ln  = tid & 63;
  const int l15 = ln & 15;
  const int l4  = ln >> 4;
  const int wn  = tid & 63;
  const int wk8 = (tid >> 6) * 8;
  const int xr0 = tid >> 4,          xc0 = tid & 15;
  const int xr1 = (tid + 512) >> 4,  xc1 = tid & 15;
  const f32x4 zero4 = {0.f, 0.f, 0.f, 0.f};

  f32x4 acc[6];
  #pragma unroll
  for (int i = 0; i < 6; ++i) acc[i] = zero4;

  float4 xp0 = *reinterpret_cast<const float4*>(X + (size_t)(m0 + xr0) * 1024 + xc0 * 4);
  float4 xp1 = *reinterpret_cast<const float4*>(X + (size_t)(m0 + xr1) * 1024 + xc1 * 4);

  for (int kb = 0; kb < 16; ++kb) {
    __syncthreads();
    bf16x4 o0, o1;
    o0[0] = (short)f2bf(xp0.x); o0[1] = (short)f2bf(xp0.y);
    o0[2] = (short)f2bf(xp0.z); o0[3] = (short)f2bf(xp0.w);
    o1[0] = (short)f2bf(xp1.x); o1[1] = (short)f2bf(xp1.y);
    o1[2] = (short)f2bf(xp1.z); o1[3] = (short)f2bf(xp1.w);
    *reinterpret_cast<bf16x4*>(&Xl[xr0 * 72 + xc0 * 4]) = o0;
    *reinterpret_cast<bf16x4*>(&Xl[xr1 * 72 + xc1 * 4]) = o1;
    if (kb < 15) {
      xp0 = *reinterpret_cast<const float4*>(
          X + (size_t)(m0 + xr0) * 1024 + (kb + 1) * 64 + xc0 * 4);
      xp1 = *reinterpret_cast<const float4*>(
          X + (size_t)(m0 + xr1) * 1024 + (kb + 1) * 64 + xc1 * 4);
    }
    #pragma unroll
    for (int c = 0; c < 3; ++c) {
      const float* Wsrc = (c == 0) ? Wk : ((c == 1) ? Wq : Wv);
      bf16x8 w0;
      #pragma unroll
      for (int j = 0; j < 8; ++j)
        w0[j] = (short)f2bf(Wsrc[(size_t)(kb * 64 + wk8 + j) * 64 + wn]);
      *reinterpret_cast<bf16x8*>(&Wl[(c * 64 + wn) * 72 + wk8]) = w0;
    }
    __syncthreads();
    bf16x8 a0 = *reinterpret_cast<const bf16x8*>(&Xl[(mt * 16 + l15) * 72 + l4 * 8]);
    bf16x8 a1 = *reinterpret_cast<const bf16x8*>(&Xl[(mt * 16 + l15) * 72 + 32 + l4 * 8]);
    #pragma unroll
    for (int i = 0; i < 6; ++i) {
      int row = nh * 96 + i * 16 + l15;
      bf16x8 b0 = *reinterpret_cast<const bf16x8*>(&Wl[row * 72 + l4 * 8]);
      bf16x8 b1 = *reinterpret_cast<const bf16x8*>(&Wl[row * 72 + 32 + l4 * 8]);
      acc[i] = __builtin_amdgcn_mfma_f32_16x16x32_bf16(a0, b0, acc[i], 0, 0, 0);
      acc[i] = __builtin_amdgcn_mfma_f32_16x16x32_bf16(a1, b1, acc[i], 0, 0, 0);
    }
  }
  #pragma unroll
  for (int i = 0; i < 6; ++i) {
    int j = nh * 96 + i * 16 + l15;
    int mr0 = m0 + mt * 16 + l4 * 4;
    if (j < 64) {
      #pragma unroll
      for (int r = 0; r < 4; ++r)
        Kr[(size_t)(mr0 + r) * 64 + j] = f2bf(acc[i][r] + bk[j]);
    } else if (j < 128) {
      int jq = j - 64;
      #pragma unroll
      for (int r = 0; r < 4; ++r)
        Qs[(size_t)(mr0 + r) * 64 + jq] = f2bf((acc[i][r] + bq[jq]) * QSCALE);
    } else {
      int h = j - 128;
      int bb = mr0 >> 12, t0 = mr0 & 4095;
      ushort4 o;
      o.x = f2bf(acc[i][0] + bv[h]); o.y = f2bf(acc[i][1] + bv[h]);
      o.z = f2bf(acc[i][2] + bv[h]); o.w = f2bf(acc[i][3] + bv[h]);
      *reinterpret_cast<ushort4*>(&Vt[((size_t)(bb * 64 + h)) * 4096 + t0]) = o;
    }
  }
}

// ---- attn7: per-wave K(dbuf)+V LDS pipelines, kv=32, no barriers ------
__global__ __launch_bounds__(256) void attn7_kernel(
    const unsigned short* __restrict__ Qs,
    const unsigned short* __restrict__ Kr,
    const unsigned short* __restrict__ Vt,
    float* __restrict__ out) {
  __shared__ __align__(16) unsigned short Klds[4][2][32 * 64];  // 32 KB
  __shared__ __align__(16) unsigned short Vlds[4][32 * 64];     // 16 KB
  const int tid = threadIdx.x;
  const int w   = tid >> 6;            // kv residue class (0..3)
  const int ln  = tid & 63;
  const int l15 = ln & 15;
  const int l4  = ln >> 4;
  const int bid = blockIdx.x;
  const int qt  = 127 - (bid >> 2);    // longest-first
  const int b   = bid & 3;             // batch pinned per XCD
  const int qbase  = qt * 32;
  const int ntiles = qt + 1;           // 32-wide kv tiles
  const f32x4 zero4 = {0.f, 0.f, 0.f, 0.f};

  // gll source lane offsets (pre-swizzled; LDS dest is linear lane*16)
  const int kLane = (ln >> 3) * 128 + ((ln & 7) ^ (ln >> 3)) * 16;
  const int vLane = (ln >> 2) * 8192 + (((ln & 3) ^ ((ln >> 3) & 3))) * 16;
  const char* Kbase = (const char*)Kr + (size_t)b * 4096 * 128;
  const char* Vbase = (const char*)Vt + (size_t)b * 64 * 8192;

  // Q fragments, both 16-row halves (B-operand: n=q=l15, k=h)
  const unsigned short* Q0 = Qs + ((size_t)b * 4096 + qbase + l15) * 64;
  const bf16x8 qa0 = *reinterpret_cast<const bf16x8*>(Q0 + l4 * 8);
  const bf16x8 qa1 = *reinterpret_cast<const bf16x8*>(Q0 + 32 + l4 * 8);
  const bf16x8 qb0 = *reinterpret_cast<const bf16x8*>(Q0 + 1024 + l4 * 8);
  const bf16x8 qb1 = *reinterpret_cast<const bf16x8*>(Q0 + 1024 + 32 + l4 * 8);

  f32x4 accA[4], accB[4];
  #pragma unroll
  for (int i = 0; i < 4; ++i) { accA[i] = zero4; accB[i] = zero4; }
  float mA = -1e30f, lA = 0.f, mB = -1e30f, lB = 0.f;

  auto stageK = [&](int buf, int t) {
    const char* src = Kbase + (size_t)t * 4096;
    char* dst = (char*)&Klds[w][buf][0];
    #pragma unroll
    for (int c = 0; c < 4; ++c)
      gl_lds16(src + c * 1024 + kLane, dst + c * 1024 + ln * 16);
  };
  auto stageV = [&](int t) {
    const char* src = Vbase + (size_t)t * 64;
    char* dst = (char*)&Vlds[w][0];
    #pragma unroll
    for (int c = 0; c < 4; ++c)
      gl_lds16(src + (size_t)c * 16 * 8192 + vLane, dst + c * 1024 + ln * 16);
  };

  int cur = 0;
  if (w < ntiles) stageK(0, w);

  for (int t = w; t < ntiles; t += 4) {
    stageV(t);
    const bool hn = (t + 4 < ntiles);
    if (hn) stageK(cur ^ 1, t + 4);

    // wait: current K tile landed (leave this iter's V [+K-next] flying)
    if (hn) asm volatile("s_waitcnt vmcnt(8)" ::: "memory");
    else    asm volatile("s_waitcnt vmcnt(4)" ::: "memory");
    __builtin_amdgcn_sched_barrier(0);

    // ---- S^T = K Q^T : s[nt][r] = S[kv=nt*16+4*l4+r][q=l15]
    f32x4 sA[2], sB[2];
    #pragma unroll
    for (int i = 0; i < 2; ++i) { sA[i] = zero4; sB[i] = zero4; }
    __builtin_amdgcn_s_setprio(1);
    #pragma unroll
    for (int nt = 0; nt < 2; ++nt) {
      const int krow = nt * 16 + l15;
      const unsigned short* kp = &Klds[w][cur][krow * 64];
      bf16x8 k0 = *reinterpret_cast<const bf16x8*>(kp + ((l4 ^ (krow & 7)) << 3));
      bf16x8 k1 = *reinterpret_cast<const bf16x8*>(kp + (((l4 + 4) ^ (krow & 7)) << 3));
      sA[nt] = __builtin_amdgcn_mfma_f32_16x16x32_bf16(k0, qa0, sA[nt], 0, 0, 0);
      sA[nt] = __builtin_amdgcn_mfma_f32_16x16x32_bf16(k1, qa1, sA[nt], 0, 0, 0);
      sB[nt] = __builtin_amdgcn_mfma_f32_16x16x32_bf16(k0, qb0, sB[nt], 0, 0, 0);
      sB[nt] = __builtin_amdgcn_mfma_f32_16x16x32_bf16(k1, qb1, sB[nt], 0, 0, 0);
    }
    __builtin_amdgcn_s_setprio(0);

    if (t == ntiles - 1) {  // only the last tile crosses the diagonal
      const int qm = qbase + l15 - t * 32;
      #pragma unroll
      for (int nt = 0; nt < 2; ++nt)
        #pragma unroll
        for (int r = 0; r < 4; ++r) {
          int kvl = nt * 16 + 4 * l4 + r;
          if (kvl > qm)      sA[nt][r] = -1e30f;
          if (kvl > qm + 16) sB[nt][r] = -1e30f;
        }
    }

    // ---- online softmax (8 vals/lane/half; 2 shfls per reduce)
    bf16x4 paA[2], paB[2];
    {
      float x0 = fmaxf(fmaxf(sA[0][0], sA[0][1]), fmaxf(sA[0][2], sA[0][3]));
      float x1 = fmaxf(fmaxf(sA[1][0], sA[1][1]), fmaxf(sA[1][2], sA[1][3]));
      float xm = fmaxf(x0, x1);
      xm = fmaxf(xm, __shfl_xor(xm, 16));
      xm = fmaxf(xm, __shfl_xor(xm, 32));
      float mn = fmaxf(mA, xm);
      float cc = fexp2(mA - mn);
      mA = mn; lA *= cc;
      #pragma unroll
      for (int ht = 0; ht < 4; ++ht)
        #pragma unroll
        for (int r = 0; r < 4; ++r) accA[ht][r] *= cc;
      float sum = 0.f;
      #pragma unroll
      for (int nt = 0; nt < 2; ++nt) {
        #pragma unroll
        for (int r = 0; r < 4; ++r) {
          float p = fexp2(sA[nt][r] - mA);
          sA[nt][r] = p;
          paA[nt][r] = (short)f2bf(p);
        }
        sum += (sA[nt][0] + sA[nt][1]) + (sA[nt][2] + sA[nt][3]);
      }
      sum += __shfl_xor(sum, 16);
      sum += __shfl_xor(sum, 32);
      lA += sum;
    }
    {
      float x0 = fmaxf(fmaxf(sB[0][0], sB[0][1]), fmaxf(sB[0][2], sB[0][3]));
      float x1 = fmaxf(fmaxf(sB[1][0], sB[1][1]), fmaxf(sB[1][2], sB[1][3]));
      float xm = fmaxf(x0, x1);
      xm = fmaxf(xm, __shfl_xor(xm, 16));
      xm = fmaxf(xm, __shfl_xor(xm, 32));
      float mn = fmaxf(mB, xm);
      float cc = fexp2(mB - mn);
      mB = mn; lB *= cc;
      #pragma unroll
      for (int ht = 0; ht < 4; ++ht)
        #pragma unroll
        for (int r = 0; r < 4; ++r) accB[ht][r] *= cc;
      float sum = 0.f;
      #pragma unroll
      for (int nt = 0; nt < 2; ++nt) {
        #pragma unroll
        for (int r = 0; r < 4; ++r) {
          float p = fexp2(sB[nt][r] - mB);
          sB[nt][r] = p;
          paB[nt][r] = (short)f2bf(p);
        }
        sum += (sB[nt][0] + sB[nt][1]) + (sB[nt][2] + sB[nt][3]);
      }
      sum += __shfl_xor(sum, 16);
      sum += __shfl_xor(sum, 32);
      lB += sum;
    }

    // wait: this iter's V landed (K-next may still fly)
    if (hn) asm volatile("s_waitcnt vmcnt(4)" ::: "memory");
    else    asm volatile("s_waitcnt vmcnt(0)" ::: "memory");
    __builtin_amdgcn_sched_barrier(0);

    // ---- O^T += V^T P^T : A = V-frag from swizzled LDS, B = P in regs
    __builtin_amdgcn_s_setprio(1);
    #pragma unroll
    for (int nt = 0; nt < 2; ++nt) {
      #pragma unroll
      for (int ht = 0; ht < 4; ++ht) {
        const int vrow = ht * 16 + l15;
        const int g16 = (nt * 2 + (l4 >> 1)) ^ ((vrow >> 1) & 3);
        const char* vp = (const char*)&Vlds[w][0] + vrow * 64 + (g16 << 4) + ((l4 & 1) << 3);
        bf16x4 vf = *reinterpret_cast<const bf16x4*>(vp);
        accA[ht] = mfma16(vf, paA[nt], accA[ht]);
        accB[ht] = mfma16(vf, paB[nt], accB[ht]);
      }
    }
    __builtin_amdgcn_s_setprio(0);
    cur ^= 1;
  }

  // ---- exact 4-way merge; alias Klds after all compute done ----------
  __syncthreads();
  float* MOb = (float*)&Klds[0][0][0];      // [3][2][16][68] f32 (26.1KB)
  float* MLb = MOb + 3 * 2 * 16 * 68;       // [3][2][2][16]  f32
  if (w > 0) {
    const int p = w - 1;
    #pragma unroll
    for (int ht = 0; ht < 4; ++ht) {
      *reinterpret_cast<f32x4*>(&MOb[((p * 2 + 0) * 16 + l15) * 68 + ht * 16 + 4 * l4]) = accA[ht];
      *reinterpret_cast<f32x4*>(&MOb[((p * 2 + 1) * 16 + l15) * 68 + ht * 16 + 4 * l4]) = accB[ht];
    }
    if (l4 == 0) {
      MLb[((p * 2 + 0) * 2 + 0) * 16 + l15] = mA;
      MLb[((p * 2 + 0) * 2 + 1) * 16 + l15] = lA;
      MLb[((p * 2 + 1) * 2 + 0) * 16 + l15] = mB;
      MLb[((p * 2 + 1) * 2 + 1) * 16 + l15] = lB;
    }
  }
  __syncthreads();
  if (w == 0) {
    #pragma unroll
    for (int hf = 0; hf < 2; ++hf) {
      float m = hf ? mB : mA;
      float l = hf ? lB : lA;
      float m0_ = MLb[((0 * 2 + hf) * 2 + 0) * 16 + l15];
      float m1_ = MLb[((1 * 2 + hf) * 2 + 0) * 16 + l15];
      float m2_ = MLb[((2 * 2 + hf) * 2 + 0) * 16 + l15];
      float mM = fmaxf(fmaxf(m, m0_), fmaxf(m1_, m2_));
      float aS = fexp2(m - mM);
      float a0 = fexp2(m0_ - mM), a1 = fexp2(m1_ - mM), a2 = fexp2(m2_ - mM);
      float lT = l * aS + MLb[((0 * 2 + hf) * 2 + 1) * 16 + l15] * a0
               + MLb[((1 * 2 + hf) * 2 + 1) * 16 + l15] * a1
               + MLb[((2 * 2 + hf) * 2 + 1) * 16 + l15] * a2;
      float linv = 1.0f / lT;
      float* ob = out + ((size_t)b * 4096 + qbase + hf * 16 + l15) * 64;
      #pragma unroll
      for (int ht = 0; ht < 4; ++ht) {
        f32x4 ac = hf ? accB[ht] : accA[ht];
        f32x4 o0 = *reinterpret_cast<const f32x4*>(&MOb[((0 * 2 + hf) * 16 + l15) * 68 + ht * 16 + 4 * l4]);
        f32x4 o1 = *reinterpret_cast<const f32x4*>(&MOb[((1 * 2 + hf) * 16 + l15) * 68 + ht * 16 + 4 * l4]);
        f32x4 o2 = *reinterpret_cast<const f32x4*>(&MOb[((2 * 2 + hf) * 16 + l15) * 68 + ht * 16 + 4 * l4]);
        float4 o;
        o.x = (ac[0] * aS + o0[0] * a0 + o1[0] * a1 + o2[0] * a2) * linv;
        o.y = (ac[1] * aS + o0[1] * a0 + o1[1] * a1 + o2[1] * a2) * linv;
        o.z = (ac[2] * aS + o0[2] * a0 + o1[2] * a1 + o2[2] * a2) * linv;
        o.w = (ac[3] * aS + o0[3] * a0 + o1[3] * a1 + o2[3] * a2) * linv;
        *reinterpret_cast<float4*>(ob + ht * 16 + 4 * l4) = o;
      }
    }
  }
}

// ---- Plan-B fallback: old proj (no Q) + attn with Q recompute ---------
template <bool WRITE_Q>
__global__ __launch_bounds__(256) void proj_kernel(
    const float* __restrict__ X,  const float* __restrict__ Wk,
    const float* __restrict__ Wq, const float* __restrict__ Wv,
    const float* __restrict__ bk, const float* __restrict__ bq,
    const float* __restrict__ bv, unsigned short* __restrict__ Kr,
    unsigned short* __restrict__ Qs, unsigned short* __restrict__ Vt) {
  constexpr int NT = WRITE_Q ? 12 : 8;
  constexpr int NC = NT / 4;
  __shared__ __align__(16) unsigned short Xl[64 * 72];
  __shared__ __align__(16) unsigned short Wl[NT * 16 * 72];
  const int tid = threadIdx.x;
  const int m0  = blockIdx.x * 64;
  const int w   = tid >> 6;
  const int ln  = tid & 63;
  const int l15 = ln & 15;
  const int l4  = ln >> 4;
  const f32x4 zero4 = {0.f, 0.f, 0.f, 0.f};
  f32x4 acc[NT];
  #pragma unroll
  for (int i = 0; i < NT; ++i) acc[i] = zero4;
  const int wn = tid & 63;
  const int wk = (tid >> 6) * 16;
  for (int kb = 0; kb < 16; ++kb) {
    __syncthreads();
    #pragma unroll
    for (int p = 0; p < 4; ++p) {
      int chunk = tid + p * 256;
      int r = chunk >> 4, c4 = chunk & 15;
      const float4 xv = *reinterpret_cast<const float4*>(
          X + (size_t)(m0 + r) * 1024 + kb * 64 + c4 * 4);
      bf16x4 o;
      o[0] = (short)f2bf(xv.x); o[1] = (short)f2bf(xv.y);
      o[2] = (short)f2bf(xv.z); o[3] = (short)f2bf(xv.w);
      *reinterpret_cast<bf16x4*>(&Xl[r * 72 + c4 * 4]) = o;
    }
    #pragma unroll
    for (int c = 0; c < NC; ++c) {
      const float* Wsrc = (c == 0) ? Wk : ((WRITE_Q && c == 1) ? Wq : Wv);
      bf16x8 w0, w1;
      #pragma unroll
      for (int j = 0; j < 8; ++j)
        w0[j] = (short)f2bf(Wsrc[(size_t)(kb * 64 + wk + j) * 64 + wn]);
      #pragma unroll
      for (int j = 0; j < 8; ++j)
        w1[j] = (short)f2bf(Wsrc[(size_t)(kb * 64 + wk + 8 + j) * 64 + wn]);
      *reinterpret_cast<bf16x8*>(&Wl[(c * 64 + wn) * 72 + wk])     = w0;
      *reinterpret_cast<bf16x8*>(&Wl[(c * 64 + wn) * 72 + wk + 8]) = w1;
    }
    __syncthreads();
    bf16x8 a0 = *reinterpret_cast<const bf16x8*>(&Xl[(w * 16 + l15) * 72 + l4 * 8]);
    bf16x8 a1 = *reinterpret_cast<const bf16x8*>(&Xl[(w * 16 + l15) * 72 + 32 + l4 * 8]);
    #pragma unroll
    for (int nt = 0; nt < NT; ++nt) {
      bf16x8 b0 = *reinterpret_cast<const bf16x8*>(&Wl[(nt * 16 + l15) * 72 + l4 * 8]);
      bf16x8 b1 = *reinterpret_cast<const bf16x8*>(&Wl[(nt * 16 + l15) * 72 + 32 + l4 * 8]);
      acc[nt] = __builtin_amdgcn_mfma_f32_16x16x32_bf16(a0, b0, acc[nt], 0, 0, 0);
      acc[nt] = __builtin_amdgcn_mfma_f32_16x16x32_bf16(a1, b1, acc[nt], 0, 0, 0);
    }
  }
  #pragma unroll
  for (int nt = 0; nt < NT; ++nt) {
    int j = nt * 16 + l15;
    #pragma unroll
    for (int r = 0; r < 4; ++r) {
      int m = m0 + w * 16 + l4 * 4 + r;
      float v = acc[nt][r];
      if (nt < 4) {
        Kr[(size_t)m * 64 + j] = f2bf(v + bk[j]);
      } else if (WRITE_Q && nt < 8) {
        Qs[(size_t)m * 64 + (j - 64)] = f2bf((v + bq[j - 64]) * QSCALE);
      } else {
        int h = j - (WRITE_Q ? 128 : 64);
        int bb = m >> 12, t = m & 4095;
        Vt[((size_t)(bb * 64 + h)) * 4096 + t] = f2bf(v + bv[h]);
      }
    }
  }
}

__global__ __launch_bounds__(256) void attnB_kernel(
    const unsigned short* __restrict__ Kr,
    const unsigned short* __restrict__ Vt,
    const float* __restrict__ X, const float* __restrict__ Wq,
    const float* __restrict__ bq, float* __restrict__ out) {
  __shared__ __align__(16) unsigned short Kl[64 * 72];
  __shared__ __align__(16) unsigned short Vl[64 * 72];
  __shared__ __align__(16) unsigned short Pl[4 * 16 * 72];
  const int tid = threadIdx.x;
  const int w   = tid >> 6;
  const int ln  = tid & 63;
  const int l15 = ln & 15;
  const int l4  = ln >> 4;
  const int b   = blockIdx.y;
  const int q0  = blockIdx.x * 64;
  const int qrow = q0 + w * 16;
  const f32x4 zero4 = {0.f, 0.f, 0.f, 0.f};
  unsigned short* Pw = &Pl[w * 16 * 72];
  f32x4 accq[4];
  #pragma unroll
  for (int i = 0; i < 4; ++i) accq[i] = zero4;
  const int wn = tid & 63;
  const int wk = (tid >> 6) * 16;
  for (int kb = 0; kb < 16; ++kb) {
    __syncthreads();
    #pragma unroll
    for (int p = 0; p < 4; ++p) {
      int chunk = tid + p * 256;
      int r = chunk >> 4, c4 = chunk & 15;
      const float4 xv = *reinterpret_cast<const float4*>(
          X + ((size_t)b * 4096 + q0 + r) * 1024 + kb * 64 + c4 * 4);
      bf16x4 o;
      o[0] = (short)f2bf(xv.x); o[1] = (short)f2bf(xv.y);
      o[2] = (short)f2bf(xv.z); o[3] = (short)f2bf(xv.w);
      *reinterpret_cast<bf16x4*>(&Kl[r * 72 + c4 * 4]) = o;
    }
    bf16x8 w0, w1;
    #pragma unroll
    for (int j = 0; j < 8; ++j)
      w0[j] = (short)f2bf(Wq[(size_t)(kb * 64 + wk + j) * 64 + wn]);
    #pragma unroll
    for (int j = 0; j < 8; ++j)
      w1[j] = (short)f2bf(Wq[(size_t)(kb * 64 + wk + 8 + j) * 64 + wn]);
    *reinterpret_cast<bf16x8*>(&Vl[wn * 72 + wk])     = w0;
    *reinterpret_cast<bf16x8*>(&Vl[wn * 72 + wk + 8]) = w1;
    __syncthreads();
    bf16x8 a0 = *reinterpret_cast<const bf16x8*>(&Kl[(w * 16 + l15) * 72 + l4 * 8]);
    bf16x8 a1 = *reinterpret_cast<const bf16x8*>(&Kl[(w * 16 + l15) * 72 + 32 + l4 * 8]);
    #pragma unroll
    for (int nt = 0; nt < 4; ++nt) {
      bf16x8 b0 = *reinterpret_cast<const bf16x8*>(&Vl[(nt * 16 + l15) * 72 + l4 * 8]);
      bf16x8 b1 = *reinterpret_cast<const bf16x8*>(&Vl[(nt * 16 + l15) * 72 + 32 + l4 * 8]);
      accq[nt] = __builtin_amdgcn_mfma_f32_16x16x32_bf16(a0, b0, accq[nt], 0, 0, 0);
      accq[nt] = __builtin_amdgcn_mfma_f32_16x16x32_bf16(a1, b1, accq[nt], 0, 0, 0);
    }
  }
  #pragma unroll
  for (int nt = 0; nt < 4; ++nt) {
    int h = nt * 16 + l15;
    #pragma unroll
    for (int r = 0; r < 4; ++r)
      Pw[(l4 * 4 + r) * 72 + h] = f2bf((accq[nt][r] + bq[h]) * 0.125f);
  }
  asm volatile("s_waitcnt lgkmcnt(0)" ::: "memory");
  __builtin_amdgcn_sched_barrier(0);
  bf16x8 qa0 = *reinterpret_cast<const bf16x8*>(&Pw[l15 * 72 + l4 * 8]);
  bf16x8 qa1 = *reinterpret_cast<const bf16x8*>(&Pw[l15 * 72 + 32 + l4 * 8]);
  f32x4 acco[4];
  #pragma unroll
  for (int i = 0; i < 4; ++i) acco[i] = zero4;
  float mrow[4] = {-1e30f, -1e30f, -1e30f, -1e30f};
  float lrow[4] = {0.f, 0.f, 0.f, 0.f};
  const int ktmax = blockIdx.x;
  for (int kt = 0; kt <= ktmax; ++kt) {
    const int kv0 = kt * 64;
    __syncthreads();
    #pragma unroll
    for (int p = 0; p < 2; ++p) {
      int chunk = tid + p * 256;
      int r = chunk >> 3, c8 = chunk & 7;
      *reinterpret_cast<bf16x8*>(&Kl[r * 72 + c8 * 8]) =
          *reinterpret_cast<const bf16x8*>(Kr + ((size_t)b * 4096 + kv0 + r) * 64 + c8 * 8);
      *reinterpret_cast<bf16x8*>(&Vl[r * 72 + c8 * 8]) =
          *reinterpret_cast<const bf16x8*>(Vt + ((size_t)b * 64 + r) * 4096 + kv0 + c8 * 8);
    }
    __syncthreads();
    f32x4 s[4];
    #pragma unroll
    for (int i = 0; i < 4; ++i) s[i] = zero4;
    #pragma unroll
    for (int nt = 0; nt < 4; ++nt) {
      bf16x8 k0 = *reinterpret_cast<const bf16x8*>(&Kl[(nt * 16 + l15) * 72 + l4 * 8]);
      bf16x8 k1 = *reinterpret_cast<const bf16x8*>(&Kl[(nt * 16 + l15) * 72 + 32 + l4 * 8]);
      s[nt] = __builtin_amdgcn_mfma_f32_16x16x32_bf16(qa0, k0, s[nt], 0, 0, 0);
      s[nt] = __builtin_amdgcn_mfma_f32_16x16x32_bf16(qa1, k1, s[nt], 0, 0, 0);
    }
    if (kt == ktmax) {
      #pragma unroll
      for (int nt = 0; nt < 4; ++nt) {
        int kv_g = kv0 + nt * 16 + l15;
        #pragma unroll
        for (int r = 0; r < 4; ++r) {
          int q_g = qrow + l4 * 4 + r;
          if (kv_g > q_g) s[nt][r] = -1e30f;
        }
      }
    }
    #pragma unroll
    for (int r = 0; r < 4; ++r) {
      float t = fmaxf(fmaxf(s[0][r], s[1][r]), fmaxf(s[2][r], s[3][r]));
      t = fmaxf(t, __shfl_xor(t, 1));
      t = fmaxf(t, __shfl_xor(t, 2));
      t = fmaxf(t, __shfl_xor(t, 4));
      t = fmaxf(t, __shfl_xor(t, 8));
      float mnew = fmaxf(mrow[r], t);
      float cc = __expf(mrow[r] - mnew);
      mrow[r] = mnew;
      lrow[r] *= cc;
      acco[0][r] *= cc; acco[1][r] *= cc; acco[2][r] *= cc; acco[3][r] *= cc;
    }
    #pragma unroll
    for (int nt = 0; nt < 4; ++nt) {
      #pragma unroll
      for (int r = 0; r < 4; ++r) {
        float p = __expf(s[nt][r] - mrow[r]);
        s[nt][r] = p;
        Pw[(l4 * 4 + r) * 72 + nt * 16 + l15] = f2bf(p);
      }
    }
    #pragma unroll
    for (int r = 0; r < 4; ++r) {
      float t = s[0][r] + s[1][r] + s[2][r] + s[3][r];
      t += __shfl_xor(t, 1);
      t += __shfl_xor(t, 2);
      t += __shfl_xor(t, 4);
      t += __shfl_xor(t, 8);
      lrow[r] += t;
    }
    asm volatile("s_waitcnt lgkmcnt(0)" ::: "memory");
    __builtin_amdgcn_sched_barrier(0);
    #pragma unroll
    for (int ks = 0; ks < 2; ++ks) {
      bf16x8 pa = *reinterpret_cast<const bf16x8*>(&Pw[l15 * 72 + ks * 32 + l4 * 8]);
      #pragma unroll
      for (int ht = 0; ht < 4; ++ht) {
        bf16x8 vf = *reinterpret_cast<const bf16x8*>(&Vl[(ht * 16 + l15) * 72 + ks * 32 + l4 * 8]);
        acco[ht] = __builtin_amdgcn_mfma_f32_16x16x32_bf16(pa, vf, acco[ht], 0, 0, 0);
      }
    }
  }
  float* ob = out + ((size_t)b * 4096 + qrow) * 64;
  #pragma unroll
  for (int ht = 0; ht < 4; ++ht) {
    #pragma unroll
    for (int r = 0; r < 4; ++r) {
      ob[(l4 * 4 + r) * 64 + ht * 16 + l15] = acco[ht][r] / lrow[r];
    }
  }
}

extern "C" void kernel_launch(void* const* d_in, const int* in_sizes, int n_in,
                              void* d_out, int out_size, void* d_ws, size_t ws_size,
                              hipStream_t stream) {
  const float* X  = (const float*)d_in[0];
  const float* Wk = (const float*)d_in[1];
  const float* bk = (const float*)d_in[2];
  const float* Wq = (const float*)d_in[3];
  const float* bq = (const float*)d_in[4];
  const float* Wv = (const float*)d_in[5];
  const float* bv = (const float*)d_in[6];
  float* out = (float*)d_out;

  char* ws = (char*)d_ws;
  const size_t SZ = 2097152;  // one bf16 [B*T][64] buffer
  unsigned short* Kr = (unsigned short*)(ws);
  unsigned short* Vt = (unsigned short*)(ws + SZ);

  if (ws_size >= 3 * SZ) {
    unsigned short* Qs = (unsigned short*)(ws + 2 * SZ);
    proj4_kernel<<<256, 512, 0, stream>>>(X, Wk, Wq, Wv, bk, bq, bv, Kr, Qs, Vt);
    attn7_kernel<<<512, 256, 0, stream>>>(Qs, Kr, Vt, out);
  } else {
    proj_kernel<false><<<256, 256, 0, stream>>>(X, Wk, Wq, Wv, bk, bq, bv, Kr, nullptr, Vt);
    attnB_kernel<<<dim3(64, 4), 256, 0, stream>>>(Kr, Vt, X, Wq, bq, out);
  }
}